// Round 9
// baseline (85.893 us; speedup 1.0000x reference)
//
#include <hip/hip_runtime.h>
#include <math.h>

#define T_LEN 2048
#define LN_EPS 1e-5f

using u16x8  = __attribute__((ext_vector_type(8))) unsigned short;
using bf16x8 = __attribute__((ext_vector_type(8))) short;
using f32x4  = __attribute__((ext_vector_type(4))) float;

__device__ __forceinline__ unsigned short f2bf(float f) {
    unsigned int u = __float_as_uint(f);
    u += 0x7FFFu + ((u >> 16) & 1u);
    return (unsigned short)(u >> 16);
}
__device__ __forceinline__ float bf2f(unsigned short u) {
    return __uint_as_float(((unsigned int)u) << 16);
}

// ---------------------------------------------------------------------------
// fp32 -> bf16 weights: {w_qkv, w_out, w1, w2} = 524288 elems.
// ---------------------------------------------------------------------------
__global__ __launch_bounds__(256) void conv_w(
    const float* __restrict__ s1, const float* __restrict__ s2,
    const float* __restrict__ s3, const float* __restrict__ s4,
    unsigned short* __restrict__ dst)
{
    const int i8 = (blockIdx.x * 256 + threadIdx.x) * 8;
    const float* src; int off;
    if (i8 < 196608)      { src = s1; off = 0; }
    else if (i8 < 262144) { src = s2; off = 196608; }
    else if (i8 < 393216) { src = s3; off = 262144; }
    else                  { src = s4; off = 393216; }
    const float4 a = *(const float4*)(src + (i8 - off));
    const float4 c = *(const float4*)(src + (i8 - off) + 4);
    u16x8 p;
    p[0] = f2bf(a.x); p[1] = f2bf(a.y); p[2] = f2bf(a.z); p[3] = f2bf(a.w);
    p[4] = f2bf(c.x); p[5] = f2bf(c.y); p[6] = f2bf(c.z); p[7] = f2bf(c.w);
    *(u16x8*)(dst + i8) = p;
}

// ---------------------------------------------------------------------------
// mega16: one block = 16 output rows, 256 threads (4 waves), 512 blocks
// (2 blocks/CU; LDS 48.5 KB allows 3). Phases, all block-local:
//  P0 features rows [t0-4, t0+27] -> smF[32][256] bf16 (swizzled)
//  P1 qkv 32x768 (store rows<24) -> smQ[16][256], smK/V[24][256]
//  P2 windowed attention (skip-max, 1-pass) -> smA[16][256] (aliases smF)
//  P3 out-proj + res + LN1 -> x in smA (xres kept in regs)
//  P4 FFN1 relu -> smH[16][512] (aliases smK/V)
//  P5 FFN2 + xres + LN2 -> out (f32)
// Weight fragments load global(bf16)->VGPR directly. Real loops (unroll 1).
// ---------------------------------------------------------------------------
__global__ __launch_bounds__(256) void mega16(
    const float* __restrict__ features,
    const unsigned short* __restrict__ Wqkv, const float* __restrict__ b_qkv,
    const unsigned short* __restrict__ Wo, const float* __restrict__ b_out,
    const unsigned short* __restrict__ W1, const float* __restrict__ b1,
    const unsigned short* __restrict__ W2, const float* __restrict__ b2,
    const float* __restrict__ g1, const float* __restrict__ be1,
    const float* __restrict__ g2, const float* __restrict__ be2,
    float* __restrict__ out)
{
    __shared__ __align__(16) char sm[49664];
    char* smK = sm;                      // [24][512B] = 12288
    char* smV = sm + 12288;              // [24][512B] = 12288
    char* smF = sm + 24576;              // [32][512B] = 16384
    char* smA = sm + 24576;              // alias: [16][512B] = 8192
    char* smQ = sm + 40960;              // [16][512B] = 8192
    float* part = (float*)(sm + 49152);  // [4][16][2] = 512 B
    char* smH = sm;                      // alias: [16][1024B] = 16384

    const int tid = threadIdx.x, lane = tid & 63, wid = tid >> 6;
    const int m0 = blockIdx.x * 16;
    const int b = m0 >> 11, t0 = m0 & 2047;

    // ================= P0: features halo -> smF =================
    #pragma unroll 1
    for (int it = 0; it < 4; ++it) {
        const int i = it * 256 + tid;          // 1024 chunks of 16 B
        const int e = i >> 5, ch = i & 31;
        const int gt = min(max(t0 - 4 + e, 0), T_LEN - 1);
        const float* src = features + ((size_t)(b * T_LEN + gt)) * 256 + ch * 8;
        const float4 a = *(const float4*)src;
        const float4 c = *(const float4*)(src + 4);
        u16x8 p;
        p[0] = f2bf(a.x); p[1] = f2bf(a.y); p[2] = f2bf(a.z); p[3] = f2bf(a.w);
        p[4] = f2bf(c.x); p[5] = f2bf(c.y); p[6] = f2bf(c.z); p[7] = f2bf(c.w);
        *(u16x8*)(smF + e * 512 + ((ch ^ (e & 7)) << 4)) = p;
    }
    __syncthreads();

    // ================= P1: qkv 32x768 -> smQ/K/V =================
    #pragma unroll 1
    for (int nc = 0; nc < 6; ++nc) {
        f32x4 acc[2][2];
        #pragma unroll
        for (int m = 0; m < 2; ++m)
            #pragma unroll
            for (int n = 0; n < 2; ++n) acc[m][n] = (f32x4)(0.f);

        #pragma unroll 1
        for (int kg = 0; kg < 2; ++kg) {
            bf16x8 bfr[2][4], af[2][4];
            #pragma unroll
            for (int n = 0; n < 2; ++n)
                #pragma unroll
                for (int ks = 0; ks < 4; ++ks) {
                    const int row = nc * 128 + wid * 32 + n * 16 + (lane & 15);
                    bfr[n][ks] = *(const bf16x8*)(Wqkv + (size_t)row * 256
                                 + kg * 128 + ks * 32 + (lane >> 4) * 8);
                }
            #pragma unroll
            for (int m = 0; m < 2; ++m)
                #pragma unroll
                for (int ks = 0; ks < 4; ++ks) {
                    const int r = m * 16 + (lane & 15);
                    const int ch = kg * 16 + ks * 4 + (lane >> 4);
                    af[m][ks] = *(const bf16x8*)(smF + r * 512 + ((ch ^ (r & 7)) << 4));
                }
            #pragma unroll
            for (int ks = 0; ks < 4; ++ks)
                #pragma unroll
                for (int m = 0; m < 2; ++m)
                    #pragma unroll
                    for (int n = 0; n < 2; ++n)
                        acc[m][n] = __builtin_amdgcn_mfma_f32_16x16x32_bf16(
                            af[m][ks], bfr[n][ks], acc[m][n], 0, 0, 0);
        }
        // epilogue: rows<24 -> smK/V; Q rows 4..19 -> smQ
        #pragma unroll
        for (int n = 0; n < 2; ++n) {
            const int c768 = nc * 128 + wid * 32 + n * 16 + (lane & 15);
            const float bv = b_qkv[c768];
            const int seg = c768 >> 8, cc = c768 & 255;
            #pragma unroll
            for (int m = 0; m < 2; ++m) {
                #pragma unroll
                for (int j = 0; j < 4; ++j) {
                    const int r24 = m * 16 + ((lane >> 4) << 2) + j;
                    const unsigned short h16 = f2bf(acc[m][n][j] + bv);
                    if (r24 < 24) {
                        const int off = r24 * 512 + (((cc >> 3) ^ (r24 & 7)) << 4) + ((cc & 7) << 1);
                        if (seg == 1)      *(unsigned short*)(smK + off) = h16;
                        else if (seg == 2) *(unsigned short*)(smV + off) = h16;
                        else if (r24 >= 4 && r24 < 20) {
                            const int qr = r24 - 4;
                            const int qoff = qr * 512 + (((cc >> 3) ^ (qr & 7)) << 4) + ((cc & 7) << 1);
                            *(unsigned short*)(smQ + qoff) = h16;
                        }
                    }
                }
            }
        }
    }
    __syncthreads();

    // ================= P2: attention (2 threads per (t,h)) =================
    {
        const int half = tid & 1, p = tid >> 1;
        const int h = p & 7, tl = p >> 3;          // tl 0..15, h 0..7

        float q[16];
        #pragma unroll
        for (int jj = 0; jj < 2; ++jj) {
            const int ch = h * 4 + half * 2 + jj;
            u16x8 u = *(const u16x8*)(smQ + tl * 512 + ((ch ^ (tl & 7)) << 4));
            #pragma unroll
            for (int e = 0; e < 8; ++e) q[jj * 8 + e] = bf2f(u[e]);
        }

        float sum = 0.f, ov[16];
        #pragma unroll
        for (int e = 0; e < 16; ++e) ov[e] = 0.f;

        #pragma unroll 1
        for (int j = 0; j < 9; ++j) {
            const int r24 = tl + j;
            const int kt = t0 + tl - 4 + j;
            float d = 0.f;
            #pragma unroll
            for (int jj = 0; jj < 2; ++jj) {
                const int ch = h * 4 + half * 2 + jj;
                u16x8 u = *(const u16x8*)(smK + r24 * 512 + ((ch ^ (r24 & 7)) << 4));
                #pragma unroll
                for (int e = 0; e < 8; ++e) d += q[jj * 8 + e] * bf2f(u[e]);
            }
            d += __shfl_xor(d, 1);
            // scores are tiny (|s|<~5): skip-max softmax is exact here
            const float e_ = (kt >= 0 && kt < T_LEN)
                           ? __expf(d * 0.17677669529663687f) : 0.f;
            sum += e_;
            #pragma unroll
            for (int jj = 0; jj < 2; ++jj) {
                const int ch = h * 4 + half * 2 + jj;
                u16x8 u = *(const u16x8*)(smV + r24 * 512 + ((ch ^ (r24 & 7)) << 4));
                #pragma unroll
                for (int e = 0; e < 8; ++e) ov[jj * 8 + e] += e_ * bf2f(u[e]);
            }
        }
        const float inv = 1.f / sum;
        #pragma unroll
        for (int jj = 0; jj < 2; ++jj) {
            u16x8 p8;
            #pragma unroll
            for (int e = 0; e < 8; ++e) p8[e] = f2bf(ov[jj * 8 + e] * inv);
            const int ch = h * 4 + half * 2 + jj;
            *(u16x8*)(smA + tl * 512 + ((ch ^ (tl & 7)) << 4)) = p8;
        }
    }
    __syncthreads();

    // ================= P3: out-proj + res + LN1 -> x =================
    float xres[4][4];    // [n][j]
    {
        f32x4 acc[4];
        #pragma unroll
        for (int n = 0; n < 4; ++n) acc[n] = (f32x4)(0.f);

        #pragma unroll 1
        for (int kg = 0; kg < 4; ++kg) {
            bf16x8 bfr[4][2], af[2];
            #pragma unroll
            for (int n = 0; n < 4; ++n)
                #pragma unroll
                for (int ks = 0; ks < 2; ++ks) {
                    const int row = wid * 64 + n * 16 + (lane & 15);
                    bfr[n][ks] = *(const bf16x8*)(Wo + (size_t)row * 256
                                 + kg * 64 + ks * 32 + (lane >> 4) * 8);
                }
            #pragma unroll
            for (int ks = 0; ks < 2; ++ks) {
                const int r = lane & 15;
                const int ch = kg * 8 + ks * 4 + (lane >> 4);
                af[ks] = *(const bf16x8*)(smA + r * 512 + ((ch ^ (r & 7)) << 4));
            }
            #pragma unroll
            for (int ks = 0; ks < 2; ++ks)
                #pragma unroll
                for (int n = 0; n < 4; ++n)
                    acc[n] = __builtin_amdgcn_mfma_f32_16x16x32_bf16(
                        af[ks], bfr[n][ks], acc[n], 0, 0, 0);
        }

        float v[4][4], s[4], sq[4];
        #pragma unroll
        for (int j = 0; j < 4; ++j) { s[j] = 0.f; sq[j] = 0.f; }
        #pragma unroll
        for (int n = 0; n < 4; ++n) {
            const int c = wid * 64 + n * 16 + (lane & 15);
            const float bv = b_out[c];
            #pragma unroll
            for (int j = 0; j < 4; ++j) {
                const int r = ((lane >> 4) << 2) + j;
                float x = acc[n][j] + bv + features[(size_t)(m0 + r) * 256 + c];
                v[n][j] = x; s[j] += x; sq[j] += x * x;
            }
        }
        #pragma unroll
        for (int j = 0; j < 4; ++j) {
            #pragma unroll
            for (int msk = 1; msk <= 8; msk <<= 1) {
                s[j]  += __shfl_xor(s[j], msk);
                sq[j] += __shfl_xor(sq[j], msk);
            }
            if ((lane & 15) == 0) {
                const int r = ((lane >> 4) << 2) + j;
                part[(wid * 16 + r) * 2 + 0] = s[j];
                part[(wid * 16 + r) * 2 + 1] = sq[j];
            }
        }
        __syncthreads();
        #pragma unroll
        for (int j = 0; j < 4; ++j) {
            const int r = ((lane >> 4) << 2) + j;
            float S = 0.f, SQ = 0.f;
            #pragma unroll
            for (int w = 0; w < 4; ++w) {
                S += part[(w * 16 + r) * 2 + 0]; SQ += part[(w * 16 + r) * 2 + 1];
            }
            const float mean = S * (1.f / 256.f);
            const float var  = SQ * (1.f / 256.f) - mean * mean;
            const float rstd = rsqrtf(var + LN_EPS);
            #pragma unroll
            for (int n = 0; n < 4; ++n) {
                const int c = wid * 64 + n * 16 + (lane & 15);
                const float o = (v[n][j] - mean) * rstd * g1[c] + be1[c];
                xres[n][j] = o;
                const int off = r * 512 + (((c >> 3) ^ (r & 7)) << 4) + ((c & 7) << 1);
                *(unsigned short*)(smA + off) = f2bf(o);
            }
        }
    }
    __syncthreads();

    // ================= P4: FFN1 16x512 relu -> smH =================
    #pragma unroll 1
    for (int nh = 0; nh < 2; ++nh) {
        f32x4 acc[4];
        #pragma unroll
        for (int n = 0; n < 4; ++n) acc[n] = (f32x4)(0.f);

        #pragma unroll 1
        for (int kg = 0; kg < 4; ++kg) {
            bf16x8 bfr[4][2], af[2];
            #pragma unroll
            for (int n = 0; n < 4; ++n)
                #pragma unroll
                for (int ks = 0; ks < 2; ++ks) {
                    const int row = nh * 256 + wid * 64 + n * 16 + (lane & 15);
                    bfr[n][ks] = *(const bf16x8*)(W1 + (size_t)row * 256
                                 + kg * 64 + ks * 32 + (lane >> 4) * 8);
                }
            #pragma unroll
            for (int ks = 0; ks < 2; ++ks) {
                const int r = lane & 15;
                const int ch = kg * 8 + ks * 4 + (lane >> 4);
                af[ks] = *(const bf16x8*)(smA + r * 512 + ((ch ^ (r & 7)) << 4));
            }
            #pragma unroll
            for (int ks = 0; ks < 2; ++ks)
                #pragma unroll
                for (int n = 0; n < 4; ++n)
                    acc[n] = __builtin_amdgcn_mfma_f32_16x16x32_bf16(
                        af[ks], bfr[n][ks], acc[n], 0, 0, 0);
        }
        #pragma unroll
        for (int n = 0; n < 4; ++n) {
            const int c = nh * 256 + wid * 64 + n * 16 + (lane & 15);
            const float bv = b1[c];
            #pragma unroll
            for (int j = 0; j < 4; ++j) {
                const int r = ((lane >> 4) << 2) + j;
                const int off = r * 1024 + (((c >> 3) ^ (r & 7)) << 4) + ((c & 7) << 1);
                *(unsigned short*)(smH + off) = f2bf(fmaxf(acc[n][j] + bv, 0.f));
            }
        }
    }
    __syncthreads();

    // ================= P5: FFN2 K=512 + xres + LN2 -> out =================
    {
        f32x4 acc[4];
        #pragma unroll
        for (int n = 0; n < 4; ++n) acc[n] = (f32x4)(0.f);

        #pragma unroll 1
        for (int kg = 0; kg < 8; ++kg) {
            bf16x8 bfr[4][2], af[2];
            #pragma unroll
            for (int n = 0; n < 4; ++n)
                #pragma unroll
                for (int ks = 0; ks < 2; ++ks) {
                    const int row = wid * 64 + n * 16 + (lane & 15);
                    bfr[n][ks] = *(const bf16x8*)(W2 + (size_t)row * 512
                                 + kg * 64 + ks * 32 + (lane >> 4) * 8);
                }
            #pragma unroll
            for (int ks = 0; ks < 2; ++ks) {
                const int r = lane & 15;
                const int ch = kg * 8 + ks * 4 + (lane >> 4);     // 0..63
                af[ks] = *(const bf16x8*)(smH + r * 1024 + ((ch ^ (r & 7)) << 4));
            }
            #pragma unroll
            for (int ks = 0; ks < 2; ++ks)
                #pragma unroll
                for (int n = 0; n < 4; ++n)
                    acc[n] = __builtin_amdgcn_mfma_f32_16x16x32_bf16(
                        af[ks], bfr[n][ks], acc[n], 0, 0, 0);
        }

        float v[4][4], s[4], sq[4];
        #pragma unroll
        for (int j = 0; j < 4; ++j) { s[j] = 0.f; sq[j] = 0.f; }
        #pragma unroll
        for (int n = 0; n < 4; ++n) {
            const int c = wid * 64 + n * 16 + (lane & 15);
            const float bv = b2[c];
            #pragma unroll
            for (int j = 0; j < 4; ++j) {
                float x = acc[n][j] + bv + xres[n][j];
                v[n][j] = x; s[j] += x; sq[j] += x * x;
            }
        }
        #pragma unroll
        for (int j = 0; j < 4; ++j) {
            #pragma unroll
            for (int msk = 1; msk <= 8; msk <<= 1) {
                s[j]  += __shfl_xor(s[j], msk);
                sq[j] += __shfl_xor(sq[j], msk);
            }
            if ((lane & 15) == 0) {
                const int r = ((lane >> 4) << 2) + j;
                part[(wid * 16 + r) * 2 + 0] = s[j];
                part[(wid * 16 + r) * 2 + 1] = sq[j];
            }
        }
        __syncthreads();
        #pragma unroll
        for (int j = 0; j < 4; ++j) {
            const int r = ((lane >> 4) << 2) + j;
            float S = 0.f, SQ = 0.f;
            #pragma unroll
            for (int w = 0; w < 4; ++w) {
                S += part[(w * 16 + r) * 2 + 0]; SQ += part[(w * 16 + r) * 2 + 1];
            }
            const float mean = S * (1.f / 256.f);
            const float var  = SQ * (1.f / 256.f) - mean * mean;
            const float rstd = rsqrtf(var + LN_EPS);
            #pragma unroll
            for (int n = 0; n < 4; ++n) {
                const int c = wid * 64 + n * 16 + (lane & 15);
                out[(size_t)(m0 + r) * 256 + c] = (v[n][j] - mean) * rstd * g2[c] + be2[c];
            }
        }
    }
}

// ---------------------------------------------------------------------------
extern "C" void kernel_launch(void* const* d_in, const int* in_sizes, int n_in,
                              void* d_out, int out_size, void* d_ws, size_t ws_size,
                              hipStream_t stream) {
    const float* features = (const float*)d_in[0];
    const float* w_qkv    = (const float*)d_in[1];
    const float* b_qkv    = (const float*)d_in[2];
    const float* w_out    = (const float*)d_in[3];
    const float* b_out    = (const float*)d_in[4];
    const float* w1       = (const float*)d_in[5];
    const float* b1       = (const float*)d_in[6];
    const float* w2       = (const float*)d_in[7];
    const float* b2       = (const float*)d_in[8];
    const float* g1       = (const float*)d_in[9];
    const float* be1      = (const float*)d_in[10];
    const float* g2       = (const float*)d_in[11];
    const float* be2      = (const float*)d_in[12];
    // d_in[13] (mask) structurally determined by WIN=9 -> not read.

    unsigned short* wsu = (unsigned short*)d_ws;
    unsigned short* wqkvbf = wsu;               // 196,608
    unsigned short* woutbf = wsu + 196608;      //  65,536
    unsigned short* w1bf   = wsu + 262144;      // 131,072
    unsigned short* w2bf   = wsu + 393216;      // 131,072

    conv_w<<<256, 256, 0, stream>>>(w_qkv, w_out, w1, w2, wsu);
    mega16<<<512, 256, 0, stream>>>(
        features, wqkvbf, b_qkv, woutbf, b_out, w1bf, b1, w2bf, b2,
        g1, be1, g2, be2, (float*)d_out);
}

// Round 10
// 47.005 us; speedup vs baseline: 1.8273x; 1.8273x over previous
//
#include <hip/hip_runtime.h>
#include <math.h>

#define T_LEN 2048
#define LN_EPS 1e-5f
#define M_ROWS 8192

using u16x8  = __attribute__((ext_vector_type(8))) unsigned short;
using bf16x8 = __attribute__((ext_vector_type(8))) short;
using f32x4  = __attribute__((ext_vector_type(4))) float;

__device__ __forceinline__ unsigned short f2bf(float f) {
    unsigned int u = __float_as_uint(f);
    u += 0x7FFFu + ((u >> 16) & 1u);
    return (unsigned short)(u >> 16);
}
__device__ __forceinline__ float bf2f(unsigned short u) {
    return __uint_as_float(((unsigned int)u) << 16);
}
__device__ __forceinline__ void gload16(const void* g, void* l) {
    __builtin_amdgcn_global_load_lds(
        (const __attribute__((address_space(1))) unsigned int*)g,
        (__attribute__((address_space(3))) unsigned int*)l, 16, 0, 0);
}

// ---------------------------------------------------------------------------
// fp32 -> bf16 of {features, w_qkv, w_out, w1, w2}.
// ---------------------------------------------------------------------------
__global__ __launch_bounds__(256) void to_bf16_multi(
    const float* __restrict__ s0, const float* __restrict__ s1,
    const float* __restrict__ s2, const float* __restrict__ s3,
    const float* __restrict__ s4, unsigned short* __restrict__ dst)
{
    const long i8 = ((long)blockIdx.x * 256 + threadIdx.x) * 8;
    const float* src; long off;
    if (i8 < 2097152)      { src = s0; off = 0; }
    else if (i8 < 2293760) { src = s1; off = 2097152; }
    else if (i8 < 2359296) { src = s2; off = 2293760; }
    else if (i8 < 2490368) { src = s3; off = 2359296; }
    else                   { src = s4; off = 2490368; }
    const float4 a = *(const float4*)(src + (i8 - off));
    const float4 b = *(const float4*)(src + (i8 - off) + 4);
    u16x8 p;
    p[0] = f2bf(a.x); p[1] = f2bf(a.y); p[2] = f2bf(a.z); p[3] = f2bf(a.w);
    p[4] = f2bf(b.x); p[5] = f2bf(b.y); p[6] = f2bf(b.z); p[7] = f2bf(b.w);
    *(u16x8*)(dst + i8) = p;
}

// ---------------------------------------------------------------------------
// QKV GEMM with double-buffered prefetch: C[8192,768]=A[8192,256]@W[768,256]^T.
// 128x192 tile, 512 threads (8 waves, 2x4), grid 64x4 = 256. 2x40KB LDS.
// ---------------------------------------------------------------------------
__global__ __launch_bounds__(512) void qkv_gemm_db(
    const unsigned short* __restrict__ A, const unsigned short* __restrict__ W,
    const float* __restrict__ bias, unsigned short* __restrict__ C)
{
    __shared__ char sm[2][40960];        // per buf: As [128][64] | Bs [192][64]

    const int tid = threadIdx.x, lane = tid & 63, wid = tid >> 6;
    const int wr = wid >> 2, wcl = wid & 3;
    const int m0 = blockIdx.x * 128, n0 = blockIdx.y * 192;

    auto STAGE = [&](int k0, char* buf) {
        #pragma unroll
        for (int j = 0; j < 5; ++j) {
            const int i = j * 512 + tid;               // 0..2559
            if (i < 1024) {
                const int row = i >> 3, k8 = (i & 7) ^ (row & 7);
                gload16(A + (size_t)(m0 + row) * 256 + k0 + k8 * 8, buf + i * 16);
            } else {
                const int ii = i - 1024;
                const int row = ii >> 3, k8 = (ii & 7) ^ (row & 7);
                gload16(W + (size_t)(n0 + row) * 256 + k0 + k8 * 8,
                        buf + 16384 + ii * 16);
            }
        }
    };

    f32x4 acc[4][3];
    #pragma unroll
    for (int m = 0; m < 4; ++m)
        #pragma unroll
        for (int n = 0; n < 3; ++n) acc[m][n] = (f32x4)(0.f);

    STAGE(0, sm[0]);
    __syncthreads();

    #pragma unroll
    for (int k = 0; k < 4; ++k) {
        if (k < 3) STAGE((k + 1) * 64, sm[(k + 1) & 1]);
        char* As = sm[k & 1];
        char* Bs = sm[k & 1] + 16384;
        #pragma unroll
        for (int ks = 0; ks < 2; ++ks) {
            bf16x8 af[4], bfr[3];
            #pragma unroll
            for (int m = 0; m < 4; ++m) {
                const int row = wr * 64 + m * 16 + (lane & 15);
                const int off = (row * 128 + ks * 64 + (lane >> 4) * 16) ^ ((row & 7) << 4);
                af[m] = *(const bf16x8*)(As + off);
            }
            #pragma unroll
            for (int n = 0; n < 3; ++n) {
                const int row = wcl * 48 + n * 16 + (lane & 15);
                const int off = (row * 128 + ks * 64 + (lane >> 4) * 16) ^ ((row & 7) << 4);
                bfr[n] = *(const bf16x8*)(Bs + off);
            }
            #pragma unroll
            for (int m = 0; m < 4; ++m)
                #pragma unroll
                for (int n = 0; n < 3; ++n)
                    acc[m][n] = __builtin_amdgcn_mfma_f32_16x16x32_bf16(
                        af[m], bfr[n], acc[m][n], 0, 0, 0);
        }
        __syncthreads();
    }

    #pragma unroll
    for (int n = 0; n < 3; ++n) {
        const int c = n0 + wcl * 48 + n * 16 + (lane & 15);
        const float bv = bias[c];
        #pragma unroll
        for (int m = 0; m < 4; ++m) {
            const int rbase = m0 + wr * 64 + m * 16 + ((lane >> 4) << 2);
            #pragma unroll
            for (int j = 0; j < 4; ++j)
                C[(size_t)(rbase + j) * 768 + c] = f2bf(acc[m][n][j] + bv);
        }
    }
}

// ---------------------------------------------------------------------------
// Fused tail with double-buffered weight prefetch:
//   attn (Wo stage overlapped) -> out-proj + res + LN1 -> FFN1(relu, 8 rounds)
//   -> FFN2 + xres + LN2 -> out.  One block = 32 rows, 512 threads.
// LDS: smA[32][512B] | st0/st1 (2x32KB stage) | smH[32][1024B] | part.
// ---------------------------------------------------------------------------
__global__ __launch_bounds__(512) void tail_fused_db(
    const unsigned short* __restrict__ qkv, const unsigned short* __restrict__ Wo,
    const unsigned short* __restrict__ W1, const unsigned short* __restrict__ W2,
    const float* __restrict__ resf, const float* __restrict__ b_out,
    const float* __restrict__ g1, const float* __restrict__ be1,
    const float* __restrict__ b1, const float* __restrict__ b2,
    const float* __restrict__ g2, const float* __restrict__ be2,
    float* __restrict__ out)
{
    __shared__ __align__(16) char sm[116736];
    char* smA = sm;                      // [32][512 B]  = 16384
    char* st[2] = { sm + 16384, sm + 49152 };   // 2 x 32768 stage buffers
    char* smH = sm + 81920;              // [32][1024 B] = 32768
    float* part = (float*)(sm + 114688); // [8][32][2]

    const int tid = threadIdx.x, lane = tid & 63, wid = tid >> 6;
    const int m0 = blockIdx.x * 32;
    const int b = m0 >> 11, t0 = m0 & 2047;

    // stage one [256 rows][64 cols] bf16 weight panel (32 KB)
    auto STAGE = [&](const unsigned short* W, int ldk, int rowoff, int k0, char* dst) {
        #pragma unroll
        for (int j = 0; j < 4; ++j) {
            const int i = j * 512 + tid, row = i >> 3, k8 = (i & 7) ^ (row & 7);
            gload16(W + (size_t)(rowoff + row) * ldk + k0 + k8 * 8, dst + i * 16);
        }
    };

    // ========== phase A: windowed attention; Wo round-0 stage overlapped ==========
    STAGE(Wo, 256, 0, 0, st[0]);
    if (tid < 256) {
        const int h = tid & 7, tl = tid >> 3;
        const int t = t0 + tl;
        const unsigned short* base = qkv + (size_t)b * T_LEN * 768;

        float q[32];
        const unsigned short* qp = base + (size_t)t * 768 + h * 32;
        #pragma unroll
        for (int jj = 0; jj < 4; ++jj) {
            u16x8 u = *(const u16x8*)(qp + jj * 8);
            #pragma unroll
            for (int e = 0; e < 8; ++e) q[jj * 8 + e] = bf2f(u[e]);
        }
        const unsigned short* kbase = base + 256 + h * 32;
        const unsigned short* vbase = base + 512 + h * 32;

        float sc[9], mx = -1e30f;
        #pragma unroll
        for (int j = 0; j < 9; ++j) {
            const int kr0 = t - 4 + j;
            const int krm = min(max(kr0, 0), T_LEN - 1);
            const unsigned short* kr = kbase + (size_t)krm * 768;
            float d = 0.f;
            #pragma unroll
            for (int jj = 0; jj < 4; ++jj) {
                u16x8 u = *(const u16x8*)(kr + jj * 8);
                #pragma unroll
                for (int e = 0; e < 8; ++e) d += q[jj * 8 + e] * bf2f(u[e]);
            }
            sc[j] = (kr0 == krm) ? d * 0.17677669529663687f : -1e30f;
            mx = fmaxf(mx, sc[j]);
        }
        float sum = 0.f;
        #pragma unroll
        for (int j = 0; j < 9; ++j) { sc[j] = expf(sc[j] - mx); sum += sc[j]; }
        const float inv = 1.f / sum;

        float ov[32] = {};
        #pragma unroll
        for (int j = 0; j < 9; ++j) {
            const float p = sc[j] * inv;
            const int krm = min(max(t - 4 + j, 0), T_LEN - 1);
            const unsigned short* vr = vbase + (size_t)krm * 768;
            #pragma unroll
            for (int jj = 0; jj < 4; ++jj) {
                u16x8 u = *(const u16x8*)(vr + jj * 8);
                #pragma unroll
                for (int e = 0; e < 8; ++e) ov[jj * 8 + e] += p * bf2f(u[e]);
            }
        }
        #pragma unroll
        for (int jj = 0; jj < 4; ++jj) {
            u16x8 p8;
            #pragma unroll
            for (int e = 0; e < 8; ++e) p8[e] = f2bf(ov[jj * 8 + e]);
            const int off = tl * 512 + ((h * 4 + jj) ^ (tl & 7)) * 16;
            *(u16x8*)(smA + off) = p8;
        }
    }
    __syncthreads();

    float xres[2][2][4];   // LN1 output at this thread's (r,c) fragment slots

    // ========== phase B: out-proj 32x256 (dbuf prefetch) ==========
    {
        f32x4 acc[2][2];
        #pragma unroll
        for (int m = 0; m < 2; ++m)
            #pragma unroll
            for (int n = 0; n < 2; ++n) acc[m][n] = (f32x4)(0.f);

        #pragma unroll
        for (int k = 0; k < 4; ++k) {
            if (k < 3) STAGE(Wo, 256, 0, (k + 1) * 64, st[(k + 1) & 1]);
            char* Bs = st[k & 1];
            #pragma unroll
            for (int ks = 0; ks < 2; ++ks) {
                bf16x8 af[2], bfr[2];
                #pragma unroll
                for (int m = 0; m < 2; ++m) {
                    const int r = m * 16 + (lane & 15);
                    const int ch = k * 8 + ks * 4 + (lane >> 4);
                    af[m] = *(const bf16x8*)(smA + r * 512 + ((ch ^ (r & 7)) << 4));
                }
                #pragma unroll
                for (int n = 0; n < 2; ++n) {
                    const int rB = wid * 32 + n * 16 + (lane & 15);
                    bfr[n] = *(const bf16x8*)(Bs + rB * 128
                             + (((ks * 4 + (lane >> 4)) ^ (rB & 7)) << 4));
                }
                #pragma unroll
                for (int m = 0; m < 2; ++m)
                    #pragma unroll
                    for (int n = 0; n < 2; ++n)
                        acc[m][n] = __builtin_amdgcn_mfma_f32_16x16x32_bf16(
                            af[m], bfr[n], acc[m][n], 0, 0, 0);
            }
            __syncthreads();
        }

        // epilogue: stage W1 round-0 early; + b_out + features, LN1 -> smA + xres
        STAGE(W1, 256, 0, 0, st[0]);
        float v[2][2][4], s[2][4], sq[2][4];
        #pragma unroll
        for (int m = 0; m < 2; ++m)
            #pragma unroll
            for (int j = 0; j < 4; ++j) { s[m][j] = 0.f; sq[m][j] = 0.f; }
        #pragma unroll
        for (int n = 0; n < 2; ++n) {
            const int c = wid * 32 + n * 16 + (lane & 15);
            const float bv = b_out[c];
            #pragma unroll
            for (int m = 0; m < 2; ++m) {
                const int rb = m * 16 + ((lane >> 4) << 2);
                #pragma unroll
                for (int j = 0; j < 4; ++j) {
                    float x = acc[m][n][j] + bv + resf[(size_t)(m0 + rb + j) * 256 + c];
                    v[m][n][j] = x; s[m][j] += x; sq[m][j] += x * x;
                }
            }
        }
        #pragma unroll
        for (int m = 0; m < 2; ++m)
            #pragma unroll
            for (int j = 0; j < 4; ++j) {
                #pragma unroll
                for (int msk = 1; msk <= 8; msk <<= 1) {
                    s[m][j]  += __shfl_xor(s[m][j], msk);
                    sq[m][j] += __shfl_xor(sq[m][j], msk);
                }
                if ((lane & 15) == 0) {
                    const int r = m * 16 + ((lane >> 4) << 2) + j;
                    part[(wid * 32 + r) * 2 + 0] = s[m][j];
                    part[(wid * 32 + r) * 2 + 1] = sq[m][j];
                }
            }
        __syncthreads();
        #pragma unroll
        for (int m = 0; m < 2; ++m) {
            const int rb = m * 16 + ((lane >> 4) << 2);
            #pragma unroll
            for (int j = 0; j < 4; ++j) {
                const int r = rb + j;
                float S = 0.f, SQ = 0.f;
                #pragma unroll
                for (int w = 0; w < 8; ++w) {
                    S += part[(w * 32 + r) * 2 + 0]; SQ += part[(w * 32 + r) * 2 + 1];
                }
                const float mean = S * (1.f / 256.f);
                const float var  = SQ * (1.f / 256.f) - mean * mean;
                const float rstd = rsqrtf(var + LN_EPS);
                #pragma unroll
                for (int n = 0; n < 2; ++n) {
                    const int c = wid * 32 + n * 16 + (lane & 15);
                    const float o = (v[m][n][j] - mean) * rstd * g1[c] + be1[c];
                    xres[m][n][j] = o;
                    const int addr = r * 512 + (((c >> 3) ^ (r & 7)) << 4) + ((c & 7) << 1);
                    *(unsigned short*)(smA + addr) = f2bf(o);
                }
            }
        }
    }
    __syncthreads();

    // ========== phase C: FFN1 32x512 relu, 8 rounds of [256][64] ==========
    {
        f32x4 acc[2][2];
        #pragma unroll
        for (int m = 0; m < 2; ++m)
            #pragma unroll
            for (int n = 0; n < 2; ++n) acc[m][n] = (f32x4)(0.f);

        #pragma unroll
        for (int r8 = 0; r8 < 8; ++r8) {
            const int half = r8 >> 2, kk = r8 & 3;
            if (r8 < 7) {
                const int nr = r8 + 1;
                STAGE(W1, 256, (nr >> 2) * 256, (nr & 3) * 64, st[nr & 1]);
            } else {
                STAGE(W2, 512, 0, 0, st[0]);   // P-D round 0 (buf parity: 8&1=0)
            }
            char* Bs = st[r8 & 1];
            #pragma unroll
            for (int ks = 0; ks < 2; ++ks) {
                bf16x8 af[2], bfr[2];
                #pragma unroll
                for (int m = 0; m < 2; ++m) {
                    const int r = m * 16 + (lane & 15);
                    const int ch = kk * 8 + ks * 4 + (lane >> 4);
                    af[m] = *(const bf16x8*)(smA + r * 512 + ((ch ^ (r & 7)) << 4));
                }
                #pragma unroll
                for (int n = 0; n < 2; ++n) {
                    const int rB = wid * 32 + n * 16 + (lane & 15);
                    bfr[n] = *(const bf16x8*)(Bs + rB * 128
                             + (((ks * 4 + (lane >> 4)) ^ (rB & 7)) << 4));
                }
                #pragma unroll
                for (int m = 0; m < 2; ++m)
                    #pragma unroll
                    for (int n = 0; n < 2; ++n)
                        acc[m][n] = __builtin_amdgcn_mfma_f32_16x16x32_bf16(
                            af[m], bfr[n], acc[m][n], 0, 0, 0);
            }
            __syncthreads();
            if (kk == 3) {
                // epilogue for this half: relu(acc + b1) -> smH
                #pragma unroll
                for (int n = 0; n < 2; ++n) {
                    const int c = half * 256 + wid * 32 + n * 16 + (lane & 15);
                    const float bv = b1[c];
                    #pragma unroll
                    for (int m = 0; m < 2; ++m) {
                        const int rb = m * 16 + ((lane >> 4) << 2);
                        #pragma unroll
                        for (int j = 0; j < 4; ++j) {
                            const int rr = rb + j;
                            const int addr = rr * 1024 + (((c >> 3) ^ (rr & 7)) << 4)
                                           + ((c & 7) << 1);
                            *(unsigned short*)(smH + addr) =
                                f2bf(fmaxf(acc[m][n][j] + bv, 0.f));
                        }
                    }
                }
                #pragma unroll
                for (int m = 0; m < 2; ++m)
                    #pragma unroll
                    for (int n = 0; n < 2; ++n) acc[m][n] = (f32x4)(0.f);
            }
        }
    }
    __syncthreads();   // smH complete before P-D reads

    // ========== phase D: FFN2 32x256 K=512 (dbuf) + xres + LN2 -> out ==========
    {
        f32x4 acc[2][2];
        #pragma unroll
        for (int m = 0; m < 2; ++m)
            #pragma unroll
            for (int n = 0; n < 2; ++n) acc[m][n] = (f32x4)(0.f);

        #pragma unroll
        for (int k = 0; k < 8; ++k) {
            if (k < 7) STAGE(W2, 512, 0, (k + 1) * 64, st[(k + 1) & 1]);
            char* Bs = st[k & 1];
            #pragma unroll
            for (int ks = 0; ks < 2; ++ks) {
                bf16x8 af[2], bfr[2];
                #pragma unroll
                for (int m = 0; m < 2; ++m) {
                    const int r = m * 16 + (lane & 15);
                    const int ch = k * 8 + ks * 4 + (lane >> 4);     // 0..63
                    af[m] = *(const bf16x8*)(smH + r * 1024 + ((ch ^ (r & 7)) << 4));
                }
                #pragma unroll
                for (int n = 0; n < 2; ++n) {
                    const int rB = wid * 32 + n * 16 + (lane & 15);
                    bfr[n] = *(const bf16x8*)(Bs + rB * 128
                             + (((ks * 4 + (lane >> 4)) ^ (rB & 7)) << 4));
                }
                #pragma unroll
                for (int m = 0; m < 2; ++m)
                    #pragma unroll
                    for (int n = 0; n < 2; ++n)
                        acc[m][n] = __builtin_amdgcn_mfma_f32_16x16x32_bf16(
                            af[m], bfr[n], acc[m][n], 0, 0, 0);
            }
            __syncthreads();
        }

        // epilogue: + b2 + xres, LN2 -> out (f32)
        float v[2][2][4], s[2][4], sq[2][4];
        #pragma unroll
        for (int m = 0; m < 2; ++m)
            #pragma unroll
            for (int j = 0; j < 4; ++j) { s[m][j] = 0.f; sq[m][j] = 0.f; }
        #pragma unroll
        for (int n = 0; n < 2; ++n) {
            const int c = wid * 32 + n * 16 + (lane & 15);
            const float bv = b2[c];
            #pragma unroll
            for (int m = 0; m < 2; ++m) {
                #pragma unroll
                for (int j = 0; j < 4; ++j) {
                    float x = acc[m][n][j] + bv + xres[m][n][j];
                    v[m][n][j] = x; s[m][j] += x; sq[m][j] += x * x;
                }
            }
        }
        #pragma unroll
        for (int m = 0; m < 2; ++m)
            #pragma unroll
            for (int j = 0; j < 4; ++j) {
                #pragma unroll
                for (int msk = 1; msk <= 8; msk <<= 1) {
                    s[m][j]  += __shfl_xor(s[m][j], msk);
                    sq[m][j] += __shfl_xor(sq[m][j], msk);
                }
                if ((lane & 15) == 0) {
                    const int r = m * 16 + ((lane >> 4) << 2) + j;
                    part[(wid * 32 + r) * 2 + 0] = s[m][j];
                    part[(wid * 32 + r) * 2 + 1] = sq[m][j];
                }
            }
        __syncthreads();
        #pragma unroll
        for (int m = 0; m < 2; ++m) {
            const int rb = m * 16 + ((lane >> 4) << 2);
            #pragma unroll
            for (int j = 0; j < 4; ++j) {
                const int r = rb + j;
                float S = 0.f, SQ = 0.f;
                #pragma unroll
                for (int w = 0; w < 8; ++w) {
                    S += part[(w * 32 + r) * 2 + 0]; SQ += part[(w * 32 + r) * 2 + 1];
                }
                const float mean = S * (1.f / 256.f);
                const float var  = SQ * (1.f / 256.f) - mean * mean;
                const float rstd = rsqrtf(var + LN_EPS);
                #pragma unroll
                for (int n = 0; n < 2; ++n) {
                    const int c = wid * 32 + n * 16 + (lane & 15);
                    out[(size_t)(m0 + r) * 256 + c] =
                        (v[m][n][j] - mean) * rstd * g2[c] + be2[c];
                }
            }
        }
    }
}

// ---------------------------------------------------------------------------
extern "C" void kernel_launch(void* const* d_in, const int* in_sizes, int n_in,
                              void* d_out, int out_size, void* d_ws, size_t ws_size,
                              hipStream_t stream) {
    const float* features = (const float*)d_in[0];
    const float* w_qkv    = (const float*)d_in[1];
    const float* b_qkv    = (const float*)d_in[2];
    const float* w_out    = (const float*)d_in[3];
    const float* b_out    = (const float*)d_in[4];
    const float* w1       = (const float*)d_in[5];
    const float* b1       = (const float*)d_in[6];
    const float* w2       = (const float*)d_in[7];
    const float* b2       = (const float*)d_in[8];
    const float* g1       = (const float*)d_in[9];
    const float* be1      = (const float*)d_in[10];
    const float* g2       = (const float*)d_in[11];
    const float* be2      = (const float*)d_in[12];
    // d_in[13] (mask) structurally determined by WIN=9 -> not read.

    unsigned short* wsu = (unsigned short*)d_ws;
    unsigned short* featbf = wsu;               // 2,097,152
    unsigned short* wqkvbf = wsu + 2097152;     //   196,608
    unsigned short* woutbf = wsu + 2293760;     //    65,536
    unsigned short* w1bf   = wsu + 2359296;     //   131,072
    unsigned short* w2bf   = wsu + 2490368;     //   131,072
    unsigned short* qkvbf  = wsu + 2621440;     // [8192][768]

    // 1) convert weights + features to bf16
    to_bf16_multi<<<1280, 256, 0, stream>>>(features, w_qkv, w_out, w1, w2, wsu);
    // 2) QKV projection (double-buffered prefetch)
    qkv_gemm_db<<<dim3(64, 4), 512, 0, stream>>>(featbf, wqkvbf, b_qkv, qkvbf);
    // 3) fused tail: attn -> out-proj+LN1 -> FFN1 -> FFN2+LN2 -> out
    tail_fused_db<<<M_ROWS / 32, 512, 0, stream>>>(
        qkvbf, woutbf, w1bf, w2bf, features, b_out, g1, be1, b1, b2, g2, be2,
        (float*)d_out);
}

// Round 11
// 42.163 us; speedup vs baseline: 2.0371x; 1.1148x over previous
//
#include <hip/hip_runtime.h>
#include <math.h>

#define T_LEN 2048
#define LN_EPS 1e-5f
#define M_ROWS 8192

using u16x8  = __attribute__((ext_vector_type(8))) unsigned short;
using bf16x8 = __attribute__((ext_vector_type(8))) short;
using f32x4  = __attribute__((ext_vector_type(4))) float;

__device__ __forceinline__ unsigned short f2bf(float f) {
    unsigned int u = __float_as_uint(f);
    u += 0x7FFFu + ((u >> 16) & 1u);
    return (unsigned short)(u >> 16);
}
__device__ __forceinline__ float bf2f(unsigned short u) {
    return __uint_as_float(((unsigned int)u) << 16);
}
__device__ __forceinline__ u16x8 pack8(float4 a, float4 c) {
    u16x8 p;
    p[0] = f2bf(a.x); p[1] = f2bf(a.y); p[2] = f2bf(a.z); p[3] = f2bf(a.w);
    p[4] = f2bf(c.x); p[5] = f2bf(c.y); p[6] = f2bf(c.z); p[7] = f2bf(c.w);
    return p;
}
__device__ __forceinline__ void gload16(const void* g, void* l) {
    __builtin_amdgcn_global_load_lds(
        (const __attribute__((address_space(1))) unsigned int*)g,
        (__attribute__((address_space(3))) unsigned int*)l, 16, 0, 0);
}

// ---------------------------------------------------------------------------
// QKV GEMM from fp32 inputs (reg-staged convert, dbuf prefetch) + side job:
// convert wo/w1/w2 -> bf16 wconv for the tail kernel.
// C[8192,768] = feat[8192,256] @ Wqkv[768,256]^T + bias. 128x192 tile,
// 512 threads (8 waves, 2x4), grid 64x4 = 256.
// ---------------------------------------------------------------------------
__global__ __launch_bounds__(512) void qkv_gemm_f32(
    const float* __restrict__ A, const float* __restrict__ W,
    const float* __restrict__ bias,
    const float* __restrict__ wo, const float* __restrict__ w1,
    const float* __restrict__ w2,
    unsigned short* __restrict__ C, unsigned short* __restrict__ wconv)
{
    __shared__ char sm[2][40960];        // per buf: As [128][64] | Bs [192][64]

    const int tid = threadIdx.x, lane = tid & 63, wid = tid >> 6;
    const int wr = wid >> 2, wcl = wid & 3;
    const int m0 = blockIdx.x * 128, n0 = blockIdx.y * 192;

    // ---- side job: weight conversion (one 8-elem chunk per thread) ----
    {
        const int bid = blockIdx.y * 64 + blockIdx.x;
        const int g = bid * 512 + tid;
        if (g < 40960) {
            const int e = g * 8;
            const float* src; int off;
            if (e < 65536)       { src = wo; off = 0; }
            else if (e < 196608) { src = w1; off = 65536; }
            else                 { src = w2; off = 196608; }
            const float4 a = *(const float4*)(src + (e - off));
            const float4 c = *(const float4*)(src + (e - off) + 4);
            *(u16x8*)(wconv + e) = pack8(a, c);
        }
    }

    // staged loads for one K-round: 5 chunks/thread (2 A + 3 W), fp32
    float4 ld[5][2];
    auto LOADR = [&](int k0) {
        #pragma unroll
        for (int j = 0; j < 5; ++j) {
            const int i = j * 512 + tid;
            const float* src;
            if (i < 1024) {
                const int row = i >> 3, k8 = i & 7;
                src = A + (size_t)(m0 + row) * 256 + k0 + k8 * 8;
            } else {
                const int ii = i - 1024;
                const int row = ii >> 3, k8 = ii & 7;
                src = W + (size_t)(n0 + row) * 256 + k0 + k8 * 8;
            }
            ld[j][0] = *(const float4*)src;
            ld[j][1] = *(const float4*)(src + 4);
        }
    };
    auto CWRITE = [&](char* buf) {
        #pragma unroll
        for (int j = 0; j < 5; ++j) {
            const int i = j * 512 + tid;
            const u16x8 p = pack8(ld[j][0], ld[j][1]);
            if (i < 1024) {
                const int row = i >> 3, k8 = i & 7;
                *(u16x8*)(buf + ((row * 128 + k8 * 16) ^ ((row & 7) << 4))) = p;
            } else {
                const int ii = i - 1024;
                const int row = ii >> 3, k8 = ii & 7;
                *(u16x8*)(buf + 16384 + ((row * 128 + k8 * 16) ^ ((row & 7) << 4))) = p;
            }
        }
    };

    f32x4 acc[4][3];
    #pragma unroll
    for (int m = 0; m < 4; ++m)
        #pragma unroll
        for (int n = 0; n < 3; ++n) acc[m][n] = (f32x4)(0.f);

    LOADR(0);
    CWRITE(sm[0]);
    __syncthreads();

    #pragma unroll
    for (int k = 0; k < 4; ++k) {
        if (k < 3) LOADR((k + 1) * 64);           // prefetch into regs
        char* As = sm[k & 1];
        char* Bs = sm[k & 1] + 16384;
        #pragma unroll
        for (int ks = 0; ks < 2; ++ks) {
            bf16x8 af[4], bfr[3];
            #pragma unroll
            for (int m = 0; m < 4; ++m) {
                const int row = wr * 64 + m * 16 + (lane & 15);
                const int off = (row * 128 + ks * 64 + (lane >> 4) * 16) ^ ((row & 7) << 4);
                af[m] = *(const bf16x8*)(As + off);
            }
            #pragma unroll
            for (int n = 0; n < 3; ++n) {
                const int row = wcl * 48 + n * 16 + (lane & 15);
                const int off = (row * 128 + ks * 64 + (lane >> 4) * 16) ^ ((row & 7) << 4);
                bfr[n] = *(const bf16x8*)(Bs + off);
            }
            #pragma unroll
            for (int m = 0; m < 4; ++m)
                #pragma unroll
                for (int n = 0; n < 3; ++n)
                    acc[m][n] = __builtin_amdgcn_mfma_f32_16x16x32_bf16(
                        af[m], bfr[n], acc[m][n], 0, 0, 0);
        }
        if (k < 3) CWRITE(sm[(k + 1) & 1]);       // convert + write prefetched
        __syncthreads();
    }

    #pragma unroll
    for (int n = 0; n < 3; ++n) {
        const int c = n0 + wcl * 48 + n * 16 + (lane & 15);
        const float bv = bias[c];
        #pragma unroll
        for (int m = 0; m < 4; ++m) {
            const int rbase = m0 + wr * 64 + m * 16 + ((lane >> 4) << 2);
            #pragma unroll
            for (int j = 0; j < 4; ++j)
                C[(size_t)(rbase + j) * 768 + c] = f2bf(acc[m][n][j] + bv);
        }
    }
}

// ---------------------------------------------------------------------------
// Fused tail (dbuf weight prefetch): attn(512thr) -> out-proj+res+LN1 ->
// FFN1(relu) -> FFN2 + xres + LN2 -> out. One block = 32 rows, 512 threads.
// ---------------------------------------------------------------------------
__global__ __launch_bounds__(512) void tail_fused_db(
    const unsigned short* __restrict__ qkv, const unsigned short* __restrict__ Wo,
    const unsigned short* __restrict__ W1, const unsigned short* __restrict__ W2,
    const float* __restrict__ resf, const float* __restrict__ b_out,
    const float* __restrict__ g1, const float* __restrict__ be1,
    const float* __restrict__ b1, const float* __restrict__ b2,
    const float* __restrict__ g2, const float* __restrict__ be2,
    float* __restrict__ out)
{
    __shared__ __align__(16) char sm[116736];
    char* smA = sm;                      // [32][512 B]  = 16384
    char* st[2] = { sm + 16384, sm + 49152 };   // 2 x 32768 stage buffers
    char* smH = sm + 81920;              // [32][1024 B] = 32768
    float* part = (float*)(sm + 114688); // [8][32][2]

    const int tid = threadIdx.x, lane = tid & 63, wid = tid >> 6;
    const int m0 = blockIdx.x * 32;
    const int b = m0 >> 11, t0 = m0 & 2047;

    auto STAGE = [&](const unsigned short* W, int ldk, int rowoff, int k0, char* dst) {
        #pragma unroll
        for (int j = 0; j < 4; ++j) {
            const int i = j * 512 + tid, row = i >> 3, k8 = (i & 7) ^ (row & 7);
            gload16(W + (size_t)(rowoff + row) * ldk + k0 + k8 * 8, dst + i * 16);
        }
    };

    // ========== phase A: attention, all 512 threads (2 per (t,h)) ==========
    STAGE(Wo, 256, 0, 0, st[0]);
    {
        const int half = tid & 1, p = tid >> 1;
        const int h = p & 7, tl = p >> 3;          // tl 0..31
        const int t = t0 + tl;
        const unsigned short* base = qkv + (size_t)b * T_LEN * 768;

        float q[16];
        const unsigned short* qp = base + (size_t)t * 768 + h * 32 + half * 16;
        #pragma unroll
        for (int jj = 0; jj < 2; ++jj) {
            u16x8 u = *(const u16x8*)(qp + jj * 8);
            #pragma unroll
            for (int e = 0; e < 8; ++e) q[jj * 8 + e] = bf2f(u[e]);
        }
        const unsigned short* kbase = base + 256 + h * 32 + half * 16;
        const unsigned short* vbase = base + 512 + h * 32 + half * 16;

        float sc[9], mx = -1e30f;
        #pragma unroll
        for (int j = 0; j < 9; ++j) {
            const int kr0 = t - 4 + j;
            const int krm = min(max(kr0, 0), T_LEN - 1);
            const unsigned short* kr = kbase + (size_t)krm * 768;
            float d = 0.f;
            #pragma unroll
            for (int jj = 0; jj < 2; ++jj) {
                u16x8 u = *(const u16x8*)(kr + jj * 8);
                #pragma unroll
                for (int e = 0; e < 8; ++e) d += q[jj * 8 + e] * bf2f(u[e]);
            }
            d += __shfl_xor(d, 1);                 // combine the two halves
            sc[j] = (kr0 == krm) ? d * 0.17677669529663687f : -1e30f;
            mx = fmaxf(mx, sc[j]);
        }
        float sum = 0.f;
        #pragma unroll
        for (int j = 0; j < 9; ++j) { sc[j] = expf(sc[j] - mx); sum += sc[j]; }
        const float inv = 1.f / sum;

        float ov[16] = {};
        #pragma unroll
        for (int j = 0; j < 9; ++j) {
            const float pj = sc[j] * inv;
            const int krm = min(max(t - 4 + j, 0), T_LEN - 1);
            const unsigned short* vr = vbase + (size_t)krm * 768;
            #pragma unroll
            for (int jj = 0; jj < 2; ++jj) {
                u16x8 u = *(const u16x8*)(vr + jj * 8);
                #pragma unroll
                for (int e = 0; e < 8; ++e) ov[jj * 8 + e] += pj * bf2f(u[e]);
            }
        }
        #pragma unroll
        for (int jj = 0; jj < 2; ++jj) {
            u16x8 p8;
            #pragma unroll
            for (int e = 0; e < 8; ++e) p8[e] = f2bf(ov[jj * 8 + e]);
            const int ch = h * 4 + half * 2 + jj;
            *(u16x8*)(smA + tl * 512 + ((ch ^ (tl & 7)) << 4)) = p8;
        }
    }
    __syncthreads();

    float xres[2][2][4];   // LN1 output at this thread's (r,c) fragment slots

    // ========== phase B: out-proj 32x256 (dbuf prefetch) ==========
    {
        f32x4 acc[2][2];
        #pragma unroll
        for (int m = 0; m < 2; ++m)
            #pragma unroll
            for (int n = 0; n < 2; ++n) acc[m][n] = (f32x4)(0.f);

        #pragma unroll
        for (int k = 0; k < 4; ++k) {
            if (k < 3) STAGE(Wo, 256, 0, (k + 1) * 64, st[(k + 1) & 1]);
            char* Bs = st[k & 1];
            #pragma unroll
            for (int ks = 0; ks < 2; ++ks) {
                bf16x8 af[2], bfr[2];
                #pragma unroll
                for (int m = 0; m < 2; ++m) {
                    const int r = m * 16 + (lane & 15);
                    const int ch = k * 8 + ks * 4 + (lane >> 4);
                    af[m] = *(const bf16x8*)(smA + r * 512 + ((ch ^ (r & 7)) << 4));
                }
                #pragma unroll
                for (int n = 0; n < 2; ++n) {
                    const int rB = wid * 32 + n * 16 + (lane & 15);
                    bfr[n] = *(const bf16x8*)(Bs + rB * 128
                             + (((ks * 4 + (lane >> 4)) ^ (rB & 7)) << 4));
                }
                #pragma unroll
                for (int m = 0; m < 2; ++m)
                    #pragma unroll
                    for (int n = 0; n < 2; ++n)
                        acc[m][n] = __builtin_amdgcn_mfma_f32_16x16x32_bf16(
                            af[m], bfr[n], acc[m][n], 0, 0, 0);
            }
            __syncthreads();
        }

        STAGE(W1, 256, 0, 0, st[0]);
        float v[2][2][4], s[2][4], sq[2][4];
        #pragma unroll
        for (int m = 0; m < 2; ++m)
            #pragma unroll
            for (int j = 0; j < 4; ++j) { s[m][j] = 0.f; sq[m][j] = 0.f; }
        #pragma unroll
        for (int n = 0; n < 2; ++n) {
            const int c = wid * 32 + n * 16 + (lane & 15);
            const float bv = b_out[c];
            #pragma unroll
            for (int m = 0; m < 2; ++m) {
                const int rb = m * 16 + ((lane >> 4) << 2);
                #pragma unroll
                for (int j = 0; j < 4; ++j) {
                    float x = acc[m][n][j] + bv + resf[(size_t)(m0 + rb + j) * 256 + c];
                    v[m][n][j] = x; s[m][j] += x; sq[m][j] += x * x;
                }
            }
        }
        #pragma unroll
        for (int m = 0; m < 2; ++m)
            #pragma unroll
            for (int j = 0; j < 4; ++j) {
                #pragma unroll
                for (int msk = 1; msk <= 8; msk <<= 1) {
                    s[m][j]  += __shfl_xor(s[m][j], msk);
                    sq[m][j] += __shfl_xor(sq[m][j], msk);
                }
                if ((lane & 15) == 0) {
                    const int r = m * 16 + ((lane >> 4) << 2) + j;
                    part[(wid * 32 + r) * 2 + 0] = s[m][j];
                    part[(wid * 32 + r) * 2 + 1] = sq[m][j];
                }
            }
        __syncthreads();
        #pragma unroll
        for (int m = 0; m < 2; ++m) {
            const int rb = m * 16 + ((lane >> 4) << 2);
            #pragma unroll
            for (int j = 0; j < 4; ++j) {
                const int r = rb + j;
                float S = 0.f, SQ = 0.f;
                #pragma unroll
                for (int w = 0; w < 8; ++w) {
                    S += part[(w * 32 + r) * 2 + 0]; SQ += part[(w * 32 + r) * 2 + 1];
                }
                const float mean = S * (1.f / 256.f);
                const float var  = SQ * (1.f / 256.f) - mean * mean;
                const float rstd = rsqrtf(var + LN_EPS);
                #pragma unroll
                for (int n = 0; n < 2; ++n) {
                    const int c = wid * 32 + n * 16 + (lane & 15);
                    const float o = (v[m][n][j] - mean) * rstd * g1[c] + be1[c];
                    xres[m][n][j] = o;
                    const int addr = r * 512 + (((c >> 3) ^ (r & 7)) << 4) + ((c & 7) << 1);
                    *(unsigned short*)(smA + addr) = f2bf(o);
                }
            }
        }
    }
    __syncthreads();

    // ========== phase C: FFN1 32x512 relu, 8 rounds of [256][64] ==========
    {
        f32x4 acc[2][2];
        #pragma unroll
        for (int m = 0; m < 2; ++m)
            #pragma unroll
            for (int n = 0; n < 2; ++n) acc[m][n] = (f32x4)(0.f);

        #pragma unroll
        for (int r8 = 0; r8 < 8; ++r8) {
            const int half = r8 >> 2, kk = r8 & 3;
            if (r8 < 7) {
                const int nr = r8 + 1;
                STAGE(W1, 256, (nr >> 2) * 256, (nr & 3) * 64, st[nr & 1]);
            } else {
                STAGE(W2, 512, 0, 0, st[0]);
            }
            char* Bs = st[r8 & 1];
            #pragma unroll
            for (int ks = 0; ks < 2; ++ks) {
                bf16x8 af[2], bfr[2];
                #pragma unroll
                for (int m = 0; m < 2; ++m) {
                    const int r = m * 16 + (lane & 15);
                    const int ch = kk * 8 + ks * 4 + (lane >> 4);
                    af[m] = *(const bf16x8*)(smA + r * 512 + ((ch ^ (r & 7)) << 4));
                }
                #pragma unroll
                for (int n = 0; n < 2; ++n) {
                    const int rB = wid * 32 + n * 16 + (lane & 15);
                    bfr[n] = *(const bf16x8*)(Bs + rB * 128
                             + (((ks * 4 + (lane >> 4)) ^ (rB & 7)) << 4));
                }
                #pragma unroll
                for (int m = 0; m < 2; ++m)
                    #pragma unroll
                    for (int n = 0; n < 2; ++n)
                        acc[m][n] = __builtin_amdgcn_mfma_f32_16x16x32_bf16(
                            af[m], bfr[n], acc[m][n], 0, 0, 0);
            }
            __syncthreads();
            if (kk == 3) {
                #pragma unroll
                for (int n = 0; n < 2; ++n) {
                    const int c = half * 256 + wid * 32 + n * 16 + (lane & 15);
                    const float bv = b1[c];
                    #pragma unroll
                    for (int m = 0; m < 2; ++m) {
                        const int rb = m * 16 + ((lane >> 4) << 2);
                        #pragma unroll
                        for (int j = 0; j < 4; ++j) {
                            const int rr = rb + j;
                            const int addr = rr * 1024 + (((c >> 3) ^ (rr & 7)) << 4)
                                           + ((c & 7) << 1);
                            *(unsigned short*)(smH + addr) =
                                f2bf(fmaxf(acc[m][n][j] + bv, 0.f));
                        }
                    }
                }
                #pragma unroll
                for (int m = 0; m < 2; ++m)
                    #pragma unroll
                    for (int n = 0; n < 2; ++n) acc[m][n] = (f32x4)(0.f);
            }
        }
    }
    __syncthreads();

    // ========== phase D: FFN2 32x256 K=512 (dbuf) + xres + LN2 -> out ==========
    {
        f32x4 acc[2][2];
        #pragma unroll
        for (int m = 0; m < 2; ++m)
            #pragma unroll
            for (int n = 0; n < 2; ++n) acc[m][n] = (f32x4)(0.f);

        #pragma unroll
        for (int k = 0; k < 8; ++k) {
            if (k < 7) STAGE(W2, 512, 0, (k + 1) * 64, st[(k + 1) & 1]);
            char* Bs = st[k & 1];
            #pragma unroll
            for (int ks = 0; ks < 2; ++ks) {
                bf16x8 af[2], bfr[2];
                #pragma unroll
                for (int m = 0; m < 2; ++m) {
                    const int r = m * 16 + (lane & 15);
                    const int ch = k * 8 + ks * 4 + (lane >> 4);
                    af[m] = *(const bf16x8*)(smH + r * 1024 + ((ch ^ (r & 7)) << 4));
                }
                #pragma unroll
                for (int n = 0; n < 2; ++n) {
                    const int rB = wid * 32 + n * 16 + (lane & 15);
                    bfr[n] = *(const bf16x8*)(Bs + rB * 128
                             + (((ks * 4 + (lane >> 4)) ^ (rB & 7)) << 4));
                }
                #pragma unroll
                for (int m = 0; m < 2; ++m)
                    #pragma unroll
                    for (int n = 0; n < 2; ++n)
                        acc[m][n] = __builtin_amdgcn_mfma_f32_16x16x32_bf16(
                            af[m], bfr[n], acc[m][n], 0, 0, 0);
            }
            __syncthreads();
        }

        float v[2][2][4], s[2][4], sq[2][4];
        #pragma unroll
        for (int m = 0; m < 2; ++m)
            #pragma unroll
            for (int j = 0; j < 4; ++j) { s[m][j] = 0.f; sq[m][j] = 0.f; }
        #pragma unroll
        for (int n = 0; n < 2; ++n) {
            const int c = wid * 32 + n * 16 + (lane & 15);
            const float bv = b2[c];
            #pragma unroll
            for (int m = 0; m < 2; ++m) {
                #pragma unroll
                for (int j = 0; j < 4; ++j) {
                    float x = acc[m][n][j] + bv + xres[m][n][j];
                    v[m][n][j] = x; s[m][j] += x; sq[m][j] += x * x;
                }
            }
        }
        #pragma unroll
        for (int m = 0; m < 2; ++m)
            #pragma unroll
            for (int j = 0; j < 4; ++j) {
                #pragma unroll
                for (int msk = 1; msk <= 8; msk <<= 1) {
                    s[m][j]  += __shfl_xor(s[m][j], msk);
                    sq[m][j] += __shfl_xor(sq[m][j], msk);
                }
                if ((lane & 15) == 0) {
                    const int r = m * 16 + ((lane >> 4) << 2) + j;
                    part[(wid * 32 + r) * 2 + 0] = s[m][j];
                    part[(wid * 32 + r) * 2 + 1] = sq[m][j];
                }
            }
        __syncthreads();
        #pragma unroll
        for (int m = 0; m < 2; ++m) {
            const int rb = m * 16 + ((lane >> 4) << 2);
            #pragma unroll
            for (int j = 0; j < 4; ++j) {
                const int r = rb + j;
                float S = 0.f, SQ = 0.f;
                #pragma unroll
                for (int w = 0; w < 8; ++w) {
                    S += part[(w * 32 + r) * 2 + 0]; SQ += part[(w * 32 + r) * 2 + 1];
                }
                const float mean = S * (1.f / 256.f);
                const float var  = SQ * (1.f / 256.f) - mean * mean;
                const float rstd = rsqrtf(var + LN_EPS);
                #pragma unroll
                for (int n = 0; n < 2; ++n) {
                    const int c = wid * 32 + n * 16 + (lane & 15);
                    out[(size_t)(m0 + r) * 256 + c] =
                        (v[m][n][j] - mean) * rstd * g2[c] + be2[c];
                }
            }
        }
    }
}

// ---------------------------------------------------------------------------
extern "C" void kernel_launch(void* const* d_in, const int* in_sizes, int n_in,
                              void* d_out, int out_size, void* d_ws, size_t ws_size,
                              hipStream_t stream) {
    const float* features = (const float*)d_in[0];
    const float* w_qkv    = (const float*)d_in[1];
    const float* b_qkv    = (const float*)d_in[2];
    const float* w_out    = (const float*)d_in[3];
    const float* b_out    = (const float*)d_in[4];
    const float* w1       = (const float*)d_in[5];
    const float* b1       = (const float*)d_in[6];
    const float* w2       = (const float*)d_in[7];
    const float* b2       = (const float*)d_in[8];
    const float* g1       = (const float*)d_in[9];
    const float* be1      = (const float*)d_in[10];
    const float* g2       = (const float*)d_in[11];
    const float* be2      = (const float*)d_in[12];
    // d_in[13] (mask) structurally determined by WIN=9 -> not read.

    unsigned short* wsu = (unsigned short*)d_ws;
    unsigned short* wconv = wsu;                // wo|w1|w2 bf16: 327,680 elems
    unsigned short* qkvbf = wsu + 327680;       // [8192][768]
    unsigned short* wobf  = wconv;
    unsigned short* w1bf  = wconv + 65536;
    unsigned short* w2bf  = wconv + 196608;

    // 1) QKV projection (fp32-direct, reg-staged convert) + weight conversion
    qkv_gemm_f32<<<dim3(64, 4), 512, 0, stream>>>(
        features, w_qkv, b_qkv, w_out, w1, w2, qkvbf, wconv);
    // 2) fused tail: attn -> out-proj+LN1 -> FFN1 -> FFN2+LN2 -> out
    tail_fused_db<<<M_ROWS / 32, 512, 0, stream>>>(
        qkvbf, wobf, w1bf, w2bf, features, b_out, g1, be1, b1, b2, g2, be2,
        (float*)d_out);
}

// Round 13
// 37.694 us; speedup vs baseline: 2.2787x; 1.1186x over previous
//
#include <hip/hip_runtime.h>
#include <math.h>

#define T_LEN 2048
#define LN_EPS 1e-5f
#define M_ROWS 8192

using u16x8  = __attribute__((ext_vector_type(8))) unsigned short;
using bf16x8 = __attribute__((ext_vector_type(8))) short;
using f32x4  = __attribute__((ext_vector_type(4))) float;

__device__ __forceinline__ unsigned short f2bf(float f) {
    unsigned int u = __float_as_uint(f);
    u += 0x7FFFu + ((u >> 16) & 1u);
    return (unsigned short)(u >> 16);
}
__device__ __forceinline__ float bf2f(unsigned short u) {
    return __uint_as_float(((unsigned int)u) << 16);
}
__device__ __forceinline__ u16x8 pack8(float4 a, float4 c) {
    u16x8 p;
    p[0] = f2bf(a.x); p[1] = f2bf(a.y); p[2] = f2bf(a.z); p[3] = f2bf(a.w);
    p[4] = f2bf(c.x); p[5] = f2bf(c.y); p[6] = f2bf(c.z); p[7] = f2bf(c.w);
    return p;
}
__device__ __forceinline__ void gload16(const void* g, void* l) {
    __builtin_amdgcn_global_load_lds(
        (const __attribute__((address_space(1))) unsigned int*)g,
        (__attribute__((address_space(3))) unsigned int*)l, 16, 0, 0);
}
// counted round-barrier: newest 4 loads may stay in flight
__device__ __forceinline__ void bar_vm4() {
    asm volatile("s_waitcnt vmcnt(4)" ::: "memory");
    __builtin_amdgcn_s_barrier();
}
// draining round-barrier (pipeline tail: no new stage issued this round)
__device__ __forceinline__ void bar_vm0() {
    asm volatile("s_waitcnt vmcnt(0)" ::: "memory");
    __builtin_amdgcn_s_barrier();
}

// ---------------------------------------------------------------------------
// QKV GEMM from fp32 inputs (reg-staged convert, dbuf prefetch) + side job:
// convert wo/w1/w2 -> bf16 wconv. 128x192 tile, 512 threads, grid 64x4.
// ---------------------------------------------------------------------------
__global__ __launch_bounds__(512) void qkv_gemm_f32(
    const float* __restrict__ A, const float* __restrict__ W,
    const float* __restrict__ bias,
    const float* __restrict__ wo, const float* __restrict__ w1,
    const float* __restrict__ w2,
    unsigned short* __restrict__ C, unsigned short* __restrict__ wconv)
{
    __shared__ char sm[2][40960];

    const int tid = threadIdx.x, lane = tid & 63, wid = tid >> 6;
    const int wr = wid >> 2, wcl = wid & 3;
    const int m0 = blockIdx.x * 128, n0 = blockIdx.y * 192;

    {   // weight conversion side job
        const int bid = blockIdx.y * 64 + blockIdx.x;
        const int g = bid * 512 + tid;
        if (g < 40960) {
            const int e = g * 8;
            const float* src; int off;
            if (e < 65536)       { src = wo; off = 0; }
            else if (e < 196608) { src = w1; off = 65536; }
            else                 { src = w2; off = 196608; }
            const float4 a = *(const float4*)(src + (e - off));
            const float4 c = *(const float4*)(src + (e - off) + 4);
            *(u16x8*)(wconv + e) = pack8(a, c);
        }
    }

    float4 ld[5][2];
    auto LOADR = [&](int k0) {
        #pragma unroll
        for (int j = 0; j < 5; ++j) {
            const int i = j * 512 + tid;
            const float* src;
            if (i < 1024) {
                const int row = i >> 3, k8 = i & 7;
                src = A + (size_t)(m0 + row) * 256 + k0 + k8 * 8;
            } else {
                const int ii = i - 1024;
                const int row = ii >> 3, k8 = ii & 7;
                src = W + (size_t)(n0 + row) * 256 + k0 + k8 * 8;
            }
            ld[j][0] = *(const float4*)src;
            ld[j][1] = *(const float4*)(src + 4);
        }
    };
    auto CWRITE = [&](char* buf) {
        #pragma unroll
        for (int j = 0; j < 5; ++j) {
            const int i = j * 512 + tid;
            const u16x8 p = pack8(ld[j][0], ld[j][1]);
            if (i < 1024) {
                const int row = i >> 3, k8 = i & 7;
                *(u16x8*)(buf + ((row * 128 + k8 * 16) ^ ((row & 7) << 4))) = p;
            } else {
                const int ii = i - 1024;
                const int row = ii >> 3, k8 = ii & 7;
                *(u16x8*)(buf + 16384 + ((row * 128 + k8 * 16) ^ ((row & 7) << 4))) = p;
            }
        }
    };

    f32x4 acc[4][3];
    #pragma unroll
    for (int m = 0; m < 4; ++m)
        #pragma unroll
        for (int n = 0; n < 3; ++n) acc[m][n] = (f32x4)(0.f);

    LOADR(0);
    CWRITE(sm[0]);
    __syncthreads();

    #pragma unroll
    for (int k = 0; k < 4; ++k) {
        if (k < 3) LOADR((k + 1) * 64);
        char* As = sm[k & 1];
        char* Bs = sm[k & 1] + 16384;
        #pragma unroll
        for (int ks = 0; ks < 2; ++ks) {
            bf16x8 af[4], bfr[3];
            #pragma unroll
            for (int m = 0; m < 4; ++m) {
                const int row = wr * 64 + m * 16 + (lane & 15);
                const int off = (row * 128 + ks * 64 + (lane >> 4) * 16) ^ ((row & 7) << 4);
                af[m] = *(const bf16x8*)(As + off);
            }
            #pragma unroll
            for (int n = 0; n < 3; ++n) {
                const int row = wcl * 48 + n * 16 + (lane & 15);
                const int off = (row * 128 + ks * 64 + (lane >> 4) * 16) ^ ((row & 7) << 4);
                bfr[n] = *(const bf16x8*)(Bs + off);
            }
            #pragma unroll
            for (int m = 0; m < 4; ++m)
                #pragma unroll
                for (int n = 0; n < 3; ++n)
                    acc[m][n] = __builtin_amdgcn_mfma_f32_16x16x32_bf16(
                        af[m], bfr[n], acc[m][n], 0, 0, 0);
        }
        if (k < 3) CWRITE(sm[(k + 1) & 1]);
        __syncthreads();
    }

    #pragma unroll
    for (int n = 0; n < 3; ++n) {
        const int c = n0 + wcl * 48 + n * 16 + (lane & 15);
        const float bv = bias[c];
        #pragma unroll
        for (int m = 0; m < 4; ++m) {
            const int rbase = m0 + wr * 64 + m * 16 + ((lane >> 4) << 2);
            #pragma unroll
            for (int j = 0; j < 4; ++j)
                C[(size_t)(rbase + j) * 768 + c] = f2bf(acc[m][n][j] + bv);
        }
    }
}

// ---------------------------------------------------------------------------
// Fused tail, T4 counted-vmcnt pipeline over 20 weight panels (3 buffers,
// depth-2 prefetch). attn(512thr) -> out-proj+res+LN1 -> FFN1(relu) ->
// FFN2 + xres + LN2 -> out. One block = 32 rows, 512 threads.
// LDS: smA 16384 | 3x32768 stage | smH 32768 | part 2048 = 149504 B.
// ---------------------------------------------------------------------------
__global__ __launch_bounds__(512) void tail_fused_pipe(
    const unsigned short* __restrict__ qkv, const unsigned short* __restrict__ Wo,
    const unsigned short* __restrict__ W1, const unsigned short* __restrict__ W2,
    const float* __restrict__ resf, const float* __restrict__ b_out,
    const float* __restrict__ g1, const float* __restrict__ be1,
    const float* __restrict__ b1, const float* __restrict__ b2,
    const float* __restrict__ g2, const float* __restrict__ be2,
    float* __restrict__ out)
{
    __shared__ __align__(16) char sm[149504];
    char* smA = sm;                      // [32][512 B]  = 16384
    // stage buffers: sm + 16384 + (i%3)*32768  (3 x 32 KB)
    char* smH = sm + 114688;             // [32][1024 B] = 32768
    float* part = (float*)(sm + 147456); // [8][32][2] = 2048 B

    const int tid = threadIdx.x, lane = tid & 63, wid = tid >> 6;
    const int m0 = blockIdx.x * 32;
    const int b = m0 >> 11, t0 = m0 & 2047;

    auto stbuf = [&](int i) -> char* { return sm + 16384 + (i % 3) * 32768; };
    auto NSTAGE = [&](int i) {
        if (i >= 20) return;
        const unsigned short* W; int ldk, ro, k0;
        if (i < 4)       { W = Wo; ldk = 256; ro = 0;                    k0 = i * 64; }
        else if (i < 12) { W = W1; ldk = 256; ro = ((i - 4) >> 2) * 256; k0 = ((i - 4) & 3) * 64; }
        else             { W = W2; ldk = 512; ro = 0;                    k0 = (i - 12) * 64; }
        char* dst = stbuf(i);
        #pragma unroll
        for (int j = 0; j < 4; ++j) {
            const int ii = j * 512 + tid, row = ii >> 3, k8 = (ii & 7) ^ (row & 7);
            gload16(W + (size_t)(ro + row) * ldk + k0 + k8 * 8, dst + ii * 16);
        }
    };

    // ---- prologue: stage rounds 0,1; latency hidden under attention ----
    NSTAGE(0); NSTAGE(1);

    // ========== attention, all 512 threads (2 per (t,h)) ==========
    {
        const int half = tid & 1, p = tid >> 1;
        const int h = p & 7, tl = p >> 3;
        const int t = t0 + tl;
        const unsigned short* base = qkv + (size_t)b * T_LEN * 768;

        float q[16];
        const unsigned short* qp = base + (size_t)t * 768 + h * 32 + half * 16;
        #pragma unroll
        for (int jj = 0; jj < 2; ++jj) {
            u16x8 u = *(const u16x8*)(qp + jj * 8);
            #pragma unroll
            for (int e = 0; e < 8; ++e) q[jj * 8 + e] = bf2f(u[e]);
        }
        const unsigned short* kbase = base + 256 + h * 32 + half * 16;
        const unsigned short* vbase = base + 512 + h * 32 + half * 16;

        float sc[9], mx = -1e30f;
        #pragma unroll
        for (int j = 0; j < 9; ++j) {
            const int kr0 = t - 4 + j;
            const int krm = min(max(kr0, 0), T_LEN - 1);
            const unsigned short* kr = kbase + (size_t)krm * 768;
            float d = 0.f;
            #pragma unroll
            for (int jj = 0; jj < 2; ++jj) {
                u16x8 u = *(const u16x8*)(kr + jj * 8);
                #pragma unroll
                for (int e = 0; e < 8; ++e) d += q[jj * 8 + e] * bf2f(u[e]);
            }
            d += __shfl_xor(d, 1);
            sc[j] = (kr0 == krm) ? d * 0.17677669529663687f : -1e30f;
            mx = fmaxf(mx, sc[j]);
        }
        float sum = 0.f;
        #pragma unroll
        for (int j = 0; j < 9; ++j) { sc[j] = expf(sc[j] - mx); sum += sc[j]; }
        const float inv = 1.f / sum;

        float ov[16] = {};
        #pragma unroll
        for (int j = 0; j < 9; ++j) {
            const float pj = sc[j] * inv;
            const int krm = min(max(t - 4 + j, 0), T_LEN - 1);
            const unsigned short* vr = vbase + (size_t)krm * 768;
            #pragma unroll
            for (int jj = 0; jj < 2; ++jj) {
                u16x8 u = *(const u16x8*)(vr + jj * 8);
                #pragma unroll
                for (int e = 0; e < 8; ++e) ov[jj * 8 + e] += pj * bf2f(u[e]);
            }
        }
        #pragma unroll
        for (int jj = 0; jj < 2; ++jj) {
            u16x8 p8;
            #pragma unroll
            for (int e = 0; e < 8; ++e) p8[e] = f2bf(ov[jj * 8 + e]);
            const int ch = h * 4 + half * 2 + jj;
            *(u16x8*)(smA + tl * 512 + ((ch ^ (tl & 7)) << 4)) = p8;
        }
    }
    __syncthreads();   // smA visible; drains stages 0,1 (complete by now)

    float xres[2][2][4];

    // ========== phase B: out-proj, rounds 0..3 ==========
    {
        f32x4 acc[2][2];
        #pragma unroll
        for (int m = 0; m < 2; ++m)
            #pragma unroll
            for (int n = 0; n < 2; ++n) acc[m][n] = (f32x4)(0.f);

        #pragma unroll
        for (int i = 0; i < 4; ++i) {
            NSTAGE(i + 2);
            char* Bs = stbuf(i);
            #pragma unroll
            for (int ks = 0; ks < 2; ++ks) {
                bf16x8 af[2], bfr[2];
                #pragma unroll
                for (int m = 0; m < 2; ++m) {
                    const int r = m * 16 + (lane & 15);
                    const int ch = i * 8 + ks * 4 + (lane >> 4);
                    af[m] = *(const bf16x8*)(smA + r * 512 + ((ch ^ (r & 7)) << 4));
                }
                #pragma unroll
                for (int n = 0; n < 2; ++n) {
                    const int rB = wid * 32 + n * 16 + (lane & 15);
                    bfr[n] = *(const bf16x8*)(Bs + rB * 128
                             + (((ks * 4 + (lane >> 4)) ^ (rB & 7)) << 4));
                }
                #pragma unroll
                for (int m = 0; m < 2; ++m)
                    #pragma unroll
                    for (int n = 0; n < 2; ++n)
                        acc[m][n] = __builtin_amdgcn_mfma_f32_16x16x32_bf16(
                            af[m], bfr[n], acc[m][n], 0, 0, 0);
            }
            bar_vm4();
        }

        // LN1 epilogue (stages 4,5 in flight underneath)
        float v[2][2][4], s[2][4], sq[2][4];
        #pragma unroll
        for (int m = 0; m < 2; ++m)
            #pragma unroll
            for (int j = 0; j < 4; ++j) { s[m][j] = 0.f; sq[m][j] = 0.f; }
        #pragma unroll
        for (int n = 0; n < 2; ++n) {
            const int c = wid * 32 + n * 16 + (lane & 15);
            const float bv = b_out[c];
            #pragma unroll
            for (int m = 0; m < 2; ++m) {
                const int rb = m * 16 + ((lane >> 4) << 2);
                #pragma unroll
                for (int j = 0; j < 4; ++j) {
                    float x = acc[m][n][j] + bv + resf[(size_t)(m0 + rb + j) * 256 + c];
                    v[m][n][j] = x; s[m][j] += x; sq[m][j] += x * x;
                }
            }
        }
        #pragma unroll
        for (int m = 0; m < 2; ++m)
            #pragma unroll
            for (int j = 0; j < 4; ++j) {
                #pragma unroll
                for (int msk = 1; msk <= 8; msk <<= 1) {
                    s[m][j]  += __shfl_xor(s[m][j], msk);
                    sq[m][j] += __shfl_xor(sq[m][j], msk);
                }
                if ((lane & 15) == 0) {
                    const int r = m * 16 + ((lane >> 4) << 2) + j;
                    part[(wid * 32 + r) * 2 + 0] = s[m][j];
                    part[(wid * 32 + r) * 2 + 1] = sq[m][j];
                }
            }
        __syncthreads();
        #pragma unroll
        for (int m = 0; m < 2; ++m) {
            const int rb = m * 16 + ((lane >> 4) << 2);
            #pragma unroll
            for (int j = 0; j < 4; ++j) {
                const int r = rb + j;
                float S = 0.f, SQ = 0.f;
                #pragma unroll
                for (int w = 0; w < 8; ++w) {
                    S += part[(w * 32 + r) * 2 + 0]; SQ += part[(w * 32 + r) * 2 + 1];
                }
                const float mean = S * (1.f / 256.f);
                const float var  = SQ * (1.f / 256.f) - mean * mean;
                const float rstd = rsqrtf(var + LN_EPS);
                #pragma unroll
                for (int n = 0; n < 2; ++n) {
                    const int c = wid * 32 + n * 16 + (lane & 15);
                    const float o = (v[m][n][j] - mean) * rstd * g1[c] + be1[c];
                    xres[m][n][j] = o;
                    const int addr = r * 512 + (((c >> 3) ^ (r & 7)) << 4) + ((c & 7) << 1);
                    *(unsigned short*)(smA + addr) = f2bf(o);
                }
            }
        }
    }
    __syncthreads();   // x in smA visible

    // ========== phase C: FFN1, rounds 4..11 ==========
    {
        f32x4 acc[2][2];
        #pragma unroll
        for (int m = 0; m < 2; ++m)
            #pragma unroll
            for (int n = 0; n < 2; ++n) acc[m][n] = (f32x4)(0.f);

        #pragma unroll
        for (int i = 4; i < 12; ++i) {
            NSTAGE(i + 2);
            const int kk = (i - 4) & 3, half = (i - 4) >> 2;
            char* Bs = stbuf(i);
            #pragma unroll
            for (int ks = 0; ks < 2; ++ks) {
                bf16x8 af[2], bfr[2];
                #pragma unroll
                for (int m = 0; m < 2; ++m) {
                    const int r = m * 16 + (lane & 15);
                    const int ch = kk * 8 + ks * 4 + (lane >> 4);
                    af[m] = *(const bf16x8*)(smA + r * 512 + ((ch ^ (r & 7)) << 4));
                }
                #pragma unroll
                for (int n = 0; n < 2; ++n) {
                    const int rB = wid * 32 + n * 16 + (lane & 15);
                    bfr[n] = *(const bf16x8*)(Bs + rB * 128
                             + (((ks * 4 + (lane >> 4)) ^ (rB & 7)) << 4));
                }
                #pragma unroll
                for (int m = 0; m < 2; ++m)
                    #pragma unroll
                    for (int n = 0; n < 2; ++n)
                        acc[m][n] = __builtin_amdgcn_mfma_f32_16x16x32_bf16(
                            af[m], bfr[n], acc[m][n], 0, 0, 0);
            }
            bar_vm4();
            if (kk == 3) {
                #pragma unroll
                for (int n = 0; n < 2; ++n) {
                    const int c = half * 256 + wid * 32 + n * 16 + (lane & 15);
                    const float bv = b1[c];
                    #pragma unroll
                    for (int m = 0; m < 2; ++m) {
                        const int rb = m * 16 + ((lane >> 4) << 2);
                        #pragma unroll
                        for (int j = 0; j < 4; ++j) {
                            const int rr = rb + j;
                            const int addr = rr * 1024 + (((c >> 3) ^ (rr & 7)) << 4)
                                           + ((c & 7) << 1);
                            *(unsigned short*)(smH + addr) =
                                f2bf(fmaxf(acc[m][n][j] + bv, 0.f));
                        }
                    }
                }
                #pragma unroll
                for (int m = 0; m < 2; ++m)
                    #pragma unroll
                    for (int n = 0; n < 2; ++n) acc[m][n] = (f32x4)(0.f);
            }
        }
    }
    __syncthreads();   // smH complete before phase D reads

    // ========== phase D: FFN2 K=512, rounds 12..19 + LN2 ==========
    {
        f32x4 acc[2][2];
        #pragma unroll
        for (int m = 0; m < 2; ++m)
            #pragma unroll
            for (int n = 0; n < 2; ++n) acc[m][n] = (f32x4)(0.f);

        #pragma unroll
        for (int i = 12; i < 20; ++i) {
            NSTAGE(i + 2);
            const int k = i - 12;
            char* Bs = stbuf(i);
            #pragma unroll
            for (int ks = 0; ks < 2; ++ks) {
                bf16x8 af[2], bfr[2];
                #pragma unroll
                for (int m = 0; m < 2; ++m) {
                    const int r = m * 16 + (lane & 15);
                    const int ch = k * 8 + ks * 4 + (lane >> 4);
                    af[m] = *(const bf16x8*)(smH + r * 1024 + ((ch ^ (r & 7)) << 4));
                }
                #pragma unroll
                for (int n = 0; n < 2; ++n) {
                    const int rB = wid * 32 + n * 16 + (lane & 15);
                    bfr[n] = *(const bf16x8*)(Bs + rB * 128
                             + (((ks * 4 + (lane >> 4)) ^ (rB & 7)) << 4));
                }
                #pragma unroll
                for (int m = 0; m < 2; ++m)
                    #pragma unroll
                    for (int n = 0; n < 2; ++n)
                        acc[m][n] = __builtin_amdgcn_mfma_f32_16x16x32_bf16(
                            af[m], bfr[n], acc[m][n], 0, 0, 0);
            }
            // tail of pipeline: once no new stage is issued (i+2>=20), the
            // newest outstanding loads ARE the next round's operand -> drain.
            if (i + 2 < 20) bar_vm4(); else bar_vm0();
        }

        // LN2 epilogue -> out
        float v[2][2][4], s[2][4], sq[2][4];
        #pragma unroll
        for (int m = 0; m < 2; ++m)
            #pragma unroll
            for (int j = 0; j < 4; ++j) { s[m][j] = 0.f; sq[m][j] = 0.f; }
        #pragma unroll
        for (int n = 0; n < 2; ++n) {
            const int c = wid * 32 + n * 16 + (lane & 15);
            const float bv = b2[c];
            #pragma unroll
            for (int m = 0; m < 2; ++m) {
                #pragma unroll
                for (int j = 0; j < 4; ++j) {
                    float x = acc[m][n][j] + bv + xres[m][n][j];
                    v[m][n][j] = x; s[m][j] += x; sq[m][j] += x * x;
                }
            }
        }
        #pragma unroll
        for (int m = 0; m < 2; ++m)
            #pragma unroll
            for (int j = 0; j < 4; ++j) {
                #pragma unroll
                for (int msk = 1; msk <= 8; msk <<= 1) {
                    s[m][j]  += __shfl_xor(s[m][j], msk);
                    sq[m][j] += __shfl_xor(sq[m][j], msk);
                }
                if ((lane & 15) == 0) {
                    const int r = m * 16 + ((lane >> 4) << 2) + j;
                    part[(wid * 32 + r) * 2 + 0] = s[m][j];
                    part[(wid * 32 + r) * 2 + 1] = sq[m][j];
                }
            }
        __syncthreads();
        #pragma unroll
        for (int m = 0; m < 2; ++m) {
            const int rb = m * 16 + ((lane >> 4) << 2);
            #pragma unroll
            for (int j = 0; j < 4; ++j) {
                const int r = rb + j;
                float S = 0.f, SQ = 0.f;
                #pragma unroll
                for (int w = 0; w < 8; ++w) {
                    S += part[(w * 32 + r) * 2 + 0]; SQ += part[(w * 32 + r) * 2 + 1];
                }
                const float mean = S * (1.f / 256.f);
                const float var  = SQ * (1.f / 256.f) - mean * mean;
                const float rstd = rsqrtf(var + LN_EPS);
                #pragma unroll
                for (int n = 0; n < 2; ++n) {
                    const int c = wid * 32 + n * 16 + (lane & 15);
                    out[(size_t)(m0 + r) * 256 + c] =
                        (v[m][n][j] - mean) * rstd * g2[c] + be2[c];
                }
            }
        }
    }
}

// ---------------------------------------------------------------------------
extern "C" void kernel_launch(void* const* d_in, const int* in_sizes, int n_in,
                              void* d_out, int out_size, void* d_ws, size_t ws_size,
                              hipStream_t stream) {
    const float* features = (const float*)d_in[0];
    const float* w_qkv    = (const float*)d_in[1];
    const float* b_qkv    = (const float*)d_in[2];
    const float* w_out    = (const float*)d_in[3];
    const float* b_out    = (const float*)d_in[4];
    const float* w1       = (const float*)d_in[5];
    const float* b1       = (const float*)d_in[6];
    const float* w2       = (const float*)d_in[7];
    const float* b2       = (const float*)d_in[8];
    const float* g1       = (const float*)d_in[9];
    const float* be1      = (const float*)d_in[10];
    const float* g2       = (const float*)d_in[11];
    const float* be2      = (const float*)d_in[12];
    // d_in[13] (mask) structurally determined by WIN=9 -> not read.

    unsigned short* wsu = (unsigned short*)d_ws;
    unsigned short* wconv = wsu;                // wo|w1|w2 bf16: 327,680 elems
    unsigned short* qkvbf = wsu + 327680;       // [8192][768]
    unsigned short* wobf  = wconv;
    unsigned short* w1bf  = wconv + 65536;
    unsigned short* w2bf  = wconv + 196608;

    // 1) QKV projection (fp32-direct) + weight conversion
    qkv_gemm_f32<<<dim3(64, 4), 512, 0, stream>>>(
        features, w_qkv, b_qkv, w_out, w1, w2, qkvbf, wconv);
    // 2) fused tail with counted-vmcnt stage pipeline
    tail_fused_pipe<<<M_ROWS / 32, 512, 0, stream>>>(
        qkvbf, wobf, w1bf, w2bf, features, b_out, g1, be1, b1, b2, g2, be2,
        (float*)d_out);
}

// Round 14
// 37.336 us; speedup vs baseline: 2.3005x; 1.0096x over previous
//
#include <hip/hip_runtime.h>
#include <math.h>

#define T_LEN 2048
#define LN_EPS 1e-5f
#define M_ROWS 8192

using u16x8  = __attribute__((ext_vector_type(8))) unsigned short;
using bf16x8 = __attribute__((ext_vector_type(8))) short;
using f32x4  = __attribute__((ext_vector_type(4))) float;

__device__ __forceinline__ unsigned short f2bf(float f) {
    unsigned int u = __float_as_uint(f);
    u += 0x7FFFu + ((u >> 16) & 1u);
    return (unsigned short)(u >> 16);
}
__device__ __forceinline__ float bf2f(unsigned short u) {
    return __uint_as_float(((unsigned int)u) << 16);
}
__device__ __forceinline__ u16x8 pack8(float4 a, float4 c) {
    u16x8 p;
    p[0] = f2bf(a.x); p[1] = f2bf(a.y); p[2] = f2bf(a.z); p[3] = f2bf(a.w);
    p[4] = f2bf(c.x); p[5] = f2bf(c.y); p[6] = f2bf(c.z); p[7] = f2bf(c.w);
    return p;
}
__device__ __forceinline__ void gload16(const void* g, void* l) {
    __builtin_amdgcn_global_load_lds(
        (const __attribute__((address_space(1))) unsigned int*)g,
        (__attribute__((address_space(3))) unsigned int*)l, 16, 0, 0);
}
// counted round-barrier: newest 4 loads may stay in flight
__device__ __forceinline__ void bar_vm4() {
    asm volatile("s_waitcnt vmcnt(4)" ::: "memory");
    __builtin_amdgcn_s_barrier();
}
// draining round-barrier (pipeline tail)
__device__ __forceinline__ void bar_vm0() {
    asm volatile("s_waitcnt vmcnt(0)" ::: "memory");
    __builtin_amdgcn_s_barrier();
}

// ---------------------------------------------------------------------------
// K,V GEMM from fp32 inputs: kv[8192,512] = feat @ Wqkv[rows 256..767]^T + b.
// 128x128 tile, 512 threads (8 waves, 2x4), grid 64x4 = 256. Reg-staged
// convert, dbuf. Side job: convert wq|wo|w1|w2 -> bf16 wconv (393216 els).
// ---------------------------------------------------------------------------
__global__ __launch_bounds__(512) void kv_gemm_f32(
    const float* __restrict__ A, const float* __restrict__ Wqkv,
    const float* __restrict__ bias,
    const float* __restrict__ wo, const float* __restrict__ w1,
    const float* __restrict__ w2,
    unsigned short* __restrict__ KV, unsigned short* __restrict__ wconv)
{
    __shared__ char sm[2][32768];        // per buf: As [128][64] | Ws [128][64]

    const int tid = threadIdx.x, lane = tid & 63, wid = tid >> 6;
    const int wr = wid >> 2, wcl = wid & 3;
    const int m0 = blockIdx.x * 128, n0 = blockIdx.y * 128;

    {   // side job: weight conversion (wq from w_qkv rows 0..255)
        const int bid = blockIdx.y * 64 + blockIdx.x;
        const int g = bid * 512 + tid;
        if (g < 49152) {
            const int e = g * 8;
            const float* src; int off;
            if (e < 65536)       { src = Wqkv; off = 0; }        // wq
            else if (e < 131072) { src = wo;   off = 65536; }
            else if (e < 262144) { src = w1;   off = 131072; }
            else                 { src = w2;   off = 262144; }
            const float4 a = *(const float4*)(src + (e - off));
            const float4 c = *(const float4*)(src + (e - off) + 4);
            *(u16x8*)(wconv + e) = pack8(a, c);
        }
    }

    float4 ld[4][2];
    auto LOADR = [&](int k0) {
        #pragma unroll
        for (int j = 0; j < 4; ++j) {
            const int i = j * 512 + tid;
            const float* src;
            if (i < 1024) {
                const int row = i >> 3, k8 = i & 7;
                src = A + (size_t)(m0 + row) * 256 + k0 + k8 * 8;
            } else {
                const int ii = i - 1024;
                const int row = ii >> 3, k8 = ii & 7;
                src = Wqkv + (size_t)(256 + n0 + row) * 256 + k0 + k8 * 8;
            }
            ld[j][0] = *(const float4*)src;
            ld[j][1] = *(const float4*)(src + 4);
        }
    };
    auto CWRITE = [&](char* buf) {
        #pragma unroll
        for (int j = 0; j < 4; ++j) {
            const int i = j * 512 + tid;
            const u16x8 p = pack8(ld[j][0], ld[j][1]);
            if (i < 1024) {
                const int row = i >> 3, k8 = i & 7;
                *(u16x8*)(buf + ((row * 128 + k8 * 16) ^ ((row & 7) << 4))) = p;
            } else {
                const int ii = i - 1024;
                const int row = ii >> 3, k8 = ii & 7;
                *(u16x8*)(buf + 16384 + ((row * 128 + k8 * 16) ^ ((row & 7) << 4))) = p;
            }
        }
    };

    f32x4 acc[4][2];
    #pragma unroll
    for (int m = 0; m < 4; ++m)
        #pragma unroll
        for (int n = 0; n < 2; ++n) acc[m][n] = (f32x4)(0.f);

    LOADR(0);
    CWRITE(sm[0]);
    __syncthreads();

    #pragma unroll
    for (int k = 0; k < 4; ++k) {
        if (k < 3) LOADR((k + 1) * 64);
        char* As = sm[k & 1];
        char* Ws = sm[k & 1] + 16384;
        #pragma unroll
        for (int ks = 0; ks < 2; ++ks) {
            bf16x8 af[4], bfr[2];
            #pragma unroll
            for (int m = 0; m < 4; ++m) {
                const int row = wr * 64 + m * 16 + (lane & 15);
                const int off = (row * 128 + ks * 64 + (lane >> 4) * 16) ^ ((row & 7) << 4);
                af[m] = *(const bf16x8*)(As + off);
            }
            #pragma unroll
            for (int n = 0; n < 2; ++n) {
                const int row = wcl * 32 + n * 16 + (lane & 15);
                const int off = (row * 128 + ks * 64 + (lane >> 4) * 16) ^ ((row & 7) << 4);
                bfr[n] = *(const bf16x8*)(Ws + off);
            }
            #pragma unroll
            for (int m = 0; m < 4; ++m)
                #pragma unroll
                for (int n = 0; n < 2; ++n)
                    acc[m][n] = __builtin_amdgcn_mfma_f32_16x16x32_bf16(
                        af[m], bfr[n], acc[m][n], 0, 0, 0);
        }
        if (k < 3) CWRITE(sm[(k + 1) & 1]);
        __syncthreads();
    }

    #pragma unroll
    for (int n = 0; n < 2; ++n) {
        const int c = n0 + wcl * 32 + n * 16 + (lane & 15);
        const float bv = bias[256 + c];
        #pragma unroll
        for (int m = 0; m < 4; ++m) {
            const int rbase = m0 + wr * 64 + m * 16 + ((lane >> 4) << 2);
            #pragma unroll
            for (int j = 0; j < 4; ++j)
                KV[(size_t)(rbase + j) * 512 + c] = f2bf(acc[m][n][j] + bv);
        }
    }
}

// ---------------------------------------------------------------------------
// Fused tail, 24-round counted-vmcnt pipeline (Wq 0-3 | Wo 4-7 | W1 8-15 |
// W2 16-23): feat->bf16 | Q GEMM | attention | out-proj+res+LN1 | FFN1 |
// FFN2+xres+LN2 -> out. One block = 32 rows, 512 threads.
// LDS: smA 16K | 3x32K stage | smH 32K (aliases smF+smQ early) | part 2K.
// ---------------------------------------------------------------------------
__global__ __launch_bounds__(512) void tail_fused_pipe2(
    const unsigned short* __restrict__ kv, const unsigned short* __restrict__ wconv,
    const float* __restrict__ features, const float* __restrict__ b_qkv,
    const float* __restrict__ b_out,
    const float* __restrict__ g1, const float* __restrict__ be1,
    const float* __restrict__ b1, const float* __restrict__ b2,
    const float* __restrict__ g2, const float* __restrict__ be2,
    float* __restrict__ out)
{
    __shared__ __align__(16) char sm[149504];
    char* smA = sm;                      // [32][512 B]  = 16384
    // stage buffers: sm + 16384 + (i%3)*32768
    char* smH = sm + 114688;             // [32][1024 B] = 32768
    char* smF = smH;                     // alias: [32][512 B] (feat bf16)
    char* smQ = smH + 16384;             // alias: [32][512 B] (Q bf16)
    float* part = (float*)(sm + 147456); // [8][32][2]

    const int tid = threadIdx.x, lane = tid & 63, wid = tid >> 6;
    const int m0 = blockIdx.x * 32;
    const int b = m0 >> 11, t0 = m0 & 2047;

    const unsigned short* Wq = wconv;
    const unsigned short* Wo = wconv + 65536;
    const unsigned short* W1 = wconv + 131072;
    const unsigned short* W2 = wconv + 262144;

    auto stbuf = [&](int i) -> char* { return sm + 16384 + (i % 3) * 32768; };
    auto NSTAGE = [&](int i) {
        if (i >= 24) return;
        const unsigned short* W; int ldk, ro, k0;
        if (i < 4)       { W = Wq; ldk = 256; ro = 0;                    k0 = i * 64; }
        else if (i < 8)  { W = Wo; ldk = 256; ro = 0;                    k0 = (i - 4) * 64; }
        else if (i < 16) { W = W1; ldk = 256; ro = ((i - 8) >> 2) * 256; k0 = ((i - 8) & 3) * 64; }
        else             { W = W2; ldk = 512; ro = 0;                    k0 = (i - 16) * 64; }
        char* dst = stbuf(i);
        #pragma unroll
        for (int j = 0; j < 4; ++j) {
            const int ii = j * 512 + tid, row = ii >> 3, k8 = (ii & 7) ^ (row & 7);
            gload16(W + (size_t)(ro + row) * ldk + k0 + k8 * 8, dst + ii * 16);
        }
    };

    NSTAGE(0); NSTAGE(1);

    // ========== P-F: features rows t0..t0+31 -> smF bf16 (swizzled) ==========
    #pragma unroll
    for (int j = 0; j < 2; ++j) {
        const int i = j * 512 + tid;          // 1024 chunks of 16 B
        const int e = i >> 5, ch = i & 31;
        const float* src = features + ((size_t)(b * T_LEN + t0 + e)) * 256 + ch * 8;
        const float4 a = *(const float4*)src;
        const float4 c = *(const float4*)(src + 4);
        *(u16x8*)(smF + e * 512 + ((ch ^ (e & 7)) << 4)) = pack8(a, c);
    }
    __syncthreads();

    // ========== P-Q: Q GEMM 32x256, rounds 0..3 ==========
    {
        f32x4 acc[2][2];
        #pragma unroll
        for (int m = 0; m < 2; ++m)
            #pragma unroll
            for (int n = 0; n < 2; ++n) acc[m][n] = (f32x4)(0.f);

        #pragma unroll
        for (int i = 0; i < 4; ++i) {
            NSTAGE(i + 2);
            char* Bs = stbuf(i);
            #pragma unroll
            for (int ks = 0; ks < 2; ++ks) {
                bf16x8 af[2], bfr[2];
                #pragma unroll
                for (int m = 0; m < 2; ++m) {
                    const int r = m * 16 + (lane & 15);
                    const int ch = i * 8 + ks * 4 + (lane >> 4);
                    af[m] = *(const bf16x8*)(smF + r * 512 + ((ch ^ (r & 7)) << 4));
                }
                #pragma unroll
                for (int n = 0; n < 2; ++n) {
                    const int rB = wid * 32 + n * 16 + (lane & 15);
                    bfr[n] = *(const bf16x8*)(Bs + rB * 128
                             + (((ks * 4 + (lane >> 4)) ^ (rB & 7)) << 4));
                }
                #pragma unroll
                for (int m = 0; m < 2; ++m)
                    #pragma unroll
                    for (int n = 0; n < 2; ++n)
                        acc[m][n] = __builtin_amdgcn_mfma_f32_16x16x32_bf16(
                            af[m], bfr[n], acc[m][n], 0, 0, 0);
            }
            bar_vm4();
        }
        // Q epilogue: + b_qkv[0..255] -> smQ (bf16, swizzled scalar writes)
        #pragma unroll
        for (int n = 0; n < 2; ++n) {
            const int c = wid * 32 + n * 16 + (lane & 15);
            const float bv = b_qkv[c];
            #pragma unroll
            for (int m = 0; m < 2; ++m) {
                const int rb = m * 16 + ((lane >> 4) << 2);
                #pragma unroll
                for (int j = 0; j < 4; ++j) {
                    const int r = rb + j;
                    const int addr = r * 512 + (((c >> 3) ^ (r & 7)) << 4) + ((c & 7) << 1);
                    *(unsigned short*)(smQ + addr) = f2bf(acc[m][n][j] + bv);
                }
            }
        }
    }
    __syncthreads();

    // ========== attention: Q from LDS, K/V from kv global ==========
    {
        const int half = tid & 1, p = tid >> 1;
        const int h = p & 7, tl = p >> 3;
        const int t = t0 + tl;
        const unsigned short* kvb = kv + (size_t)b * T_LEN * 512;

        float q[16];
        #pragma unroll
        for (int jj = 0; jj < 2; ++jj) {
            const int ch = h * 4 + half * 2 + jj;
            u16x8 u = *(const u16x8*)(smQ + tl * 512 + ((ch ^ (tl & 7)) << 4));
            #pragma unroll
            for (int e = 0; e < 8; ++e) q[jj * 8 + e] = bf2f(u[e]);
        }
        const unsigned short* kbase = kvb + h * 32 + half * 16;
        const unsigned short* vbase = kvb + 256 + h * 32 + half * 16;

        float sc[9], mx = -1e30f;
        #pragma unroll
        for (int j = 0; j < 9; ++j) {
            const int kr0 = t - 4 + j;
            const int krm = min(max(kr0, 0), T_LEN - 1);
            const unsigned short* kr = kbase + (size_t)krm * 512;
            float d = 0.f;
            #pragma unroll
            for (int jj = 0; jj < 2; ++jj) {
                u16x8 u = *(const u16x8*)(kr + jj * 8);
                #pragma unroll
                for (int e = 0; e < 8; ++e) d += q[jj * 8 + e] * bf2f(u[e]);
            }
            d += __shfl_xor(d, 1);
            sc[j] = (kr0 == krm) ? d * 0.17677669529663687f : -1e30f;
            mx = fmaxf(mx, sc[j]);
        }
        float sum = 0.f;
        #pragma unroll
        for (int j = 0; j < 9; ++j) { sc[j] = expf(sc[j] - mx); sum += sc[j]; }
        const float inv = 1.f / sum;

        float ov[16] = {};
        #pragma unroll
        for (int j = 0; j < 9; ++j) {
            const float pj = sc[j] * inv;
            const int krm = min(max(t - 4 + j, 0), T_LEN - 1);
            const unsigned short* vr = vbase + (size_t)krm * 512;
            #pragma unroll
            for (int jj = 0; jj < 2; ++jj) {
                u16x8 u = *(const u16x8*)(vr + jj * 8);
                #pragma unroll
                for (int e = 0; e < 8; ++e) ov[jj * 8 + e] += pj * bf2f(u[e]);
            }
        }
        #pragma unroll
        for (int jj = 0; jj < 2; ++jj) {
            u16x8 p8;
            #pragma unroll
            for (int e = 0; e < 8; ++e) p8[e] = f2bf(ov[jj * 8 + e]);
            const int ch = h * 4 + half * 2 + jj;
            *(u16x8*)(smA + tl * 512 + ((ch ^ (tl & 7)) << 4)) = p8;
        }
    }
    __syncthreads();

    float xres[2][2][4];

    // ========== P-B: out-proj, rounds 4..7 ==========
    {
        f32x4 acc[2][2];
        #pragma unroll
        for (int m = 0; m < 2; ++m)
            #pragma unroll
            for (int n = 0; n < 2; ++n) acc[m][n] = (f32x4)(0.f);

        #pragma unroll
        for (int i = 4; i < 8; ++i) {
            NSTAGE(i + 2);
            const int kk = i - 4;
            char* Bs = stbuf(i);
            #pragma unroll
            for (int ks = 0; ks < 2; ++ks) {
                bf16x8 af[2], bfr[2];
                #pragma unroll
                for (int m = 0; m < 2; ++m) {
                    const int r = m * 16 + (lane & 15);
                    const int ch = kk * 8 + ks * 4 + (lane >> 4);
                    af[m] = *(const bf16x8*)(smA + r * 512 + ((ch ^ (r & 7)) << 4));
                }
                #pragma unroll
                for (int n = 0; n < 2; ++n) {
                    const int rB = wid * 32 + n * 16 + (lane & 15);
                    bfr[n] = *(const bf16x8*)(Bs + rB * 128
                             + (((ks * 4 + (lane >> 4)) ^ (rB & 7)) << 4));
                }
                #pragma unroll
                for (int m = 0; m < 2; ++m)
                    #pragma unroll
                    for (int n = 0; n < 2; ++n)
                        acc[m][n] = __builtin_amdgcn_mfma_f32_16x16x32_bf16(
                            af[m], bfr[n], acc[m][n], 0, 0, 0);
            }
            bar_vm4();
        }

        // LN1 epilogue
        float v[2][2][4], s[2][4], sq[2][4];
        #pragma unroll
        for (int m = 0; m < 2; ++m)
            #pragma unroll
            for (int j = 0; j < 4; ++j) { s[m][j] = 0.f; sq[m][j] = 0.f; }
        #pragma unroll
        for (int n = 0; n < 2; ++n) {
            const int c = wid * 32 + n * 16 + (lane & 15);
            const float bv = b_out[c];
            #pragma unroll
            for (int m = 0; m < 2; ++m) {
                const int rb = m * 16 + ((lane >> 4) << 2);
                #pragma unroll
                for (int j = 0; j < 4; ++j) {
                    float x = acc[m][n][j] + bv
                            + features[(size_t)(m0 + rb + j) * 256 + c];
                    v[m][n][j] = x; s[m][j] += x; sq[m][j] += x * x;
                }
            }
        }
        #pragma unroll
        for (int m = 0; m < 2; ++m)
            #pragma unroll
            for (int j = 0; j < 4; ++j) {
                #pragma unroll
                for (int msk = 1; msk <= 8; msk <<= 1) {
                    s[m][j]  += __shfl_xor(s[m][j], msk);
                    sq[m][j] += __shfl_xor(sq[m][j], msk);
                }
                if ((lane & 15) == 0) {
                    const int r = m * 16 + ((lane >> 4) << 2) + j;
                    part[(wid * 32 + r) * 2 + 0] = s[m][j];
                    part[(wid * 32 + r) * 2 + 1] = sq[m][j];
                }
            }
        __syncthreads();
        #pragma unroll
        for (int m = 0; m < 2; ++m) {
            const int rb = m * 16 + ((lane >> 4) << 2);
            #pragma unroll
            for (int j = 0; j < 4; ++j) {
                const int r = rb + j;
                float S = 0.f, SQ = 0.f;
                #pragma unroll
                for (int w = 0; w < 8; ++w) {
                    S += part[(w * 32 + r) * 2 + 0]; SQ += part[(w * 32 + r) * 2 + 1];
                }
                const float mean = S * (1.f / 256.f);
                const float var  = SQ * (1.f / 256.f) - mean * mean;
                const float rstd = rsqrtf(var + LN_EPS);
                #pragma unroll
                for (int n = 0; n < 2; ++n) {
                    const int c = wid * 32 + n * 16 + (lane & 15);
                    const float o = (v[m][n][j] - mean) * rstd * g1[c] + be1[c];
                    xres[m][n][j] = o;
                    const int addr = r * 512 + (((c >> 3) ^ (r & 7)) << 4) + ((c & 7) << 1);
                    *(unsigned short*)(smA + addr) = f2bf(o);
                }
            }
        }
    }
    __syncthreads();

    // ========== P-C: FFN1, rounds 8..15 (writes smH; smF/smQ dead) ==========
    {
        f32x4 acc[2][2];
        #pragma unroll
        for (int m = 0; m < 2; ++m)
            #pragma unroll
            for (int n = 0; n < 2; ++n) acc[m][n] = (f32x4)(0.f);

        #pragma unroll
        for (int i = 8; i < 16; ++i) {
            NSTAGE(i + 2);
            const int kk = (i - 8) & 3, half = (i - 8) >> 2;
            char* Bs = stbuf(i);
            #pragma unroll
            for (int ks = 0; ks < 2; ++ks) {
                bf16x8 af[2], bfr[2];
                #pragma unroll
                for (int m = 0; m < 2; ++m) {
                    const int r = m * 16 + (lane & 15);
                    const int ch = kk * 8 + ks * 4 + (lane >> 4);
                    af[m] = *(const bf16x8*)(smA + r * 512 + ((ch ^ (r & 7)) << 4));
                }
                #pragma unroll
                for (int n = 0; n < 2; ++n) {
                    const int rB = wid * 32 + n * 16 + (lane & 15);
                    bfr[n] = *(const bf16x8*)(Bs + rB * 128
                             + (((ks * 4 + (lane >> 4)) ^ (rB & 7)) << 4));
                }
                #pragma unroll
                for (int m = 0; m < 2; ++m)
                    #pragma unroll
                    for (int n = 0; n < 2; ++n)
                        acc[m][n] = __builtin_amdgcn_mfma_f32_16x16x32_bf16(
                            af[m], bfr[n], acc[m][n], 0, 0, 0);
            }
            bar_vm4();
            if (kk == 3) {
                #pragma unroll
                for (int n = 0; n < 2; ++n) {
                    const int c = half * 256 + wid * 32 + n * 16 + (lane & 15);
                    const float bv = b1[c];
                    #pragma unroll
                    for (int m = 0; m < 2; ++m) {
                        const int rb = m * 16 + ((lane >> 4) << 2);
                        #pragma unroll
                        for (int j = 0; j < 4; ++j) {
                            const int rr = rb + j;
                            const int addr = rr * 1024 + (((c >> 3) ^ (rr & 7)) << 4)
                                           + ((c & 7) << 1);
                            *(unsigned short*)(smH + addr) =
                                f2bf(fmaxf(acc[m][n][j] + bv, 0.f));
                        }
                    }
                }
                #pragma unroll
                for (int m = 0; m < 2; ++m)
                    #pragma unroll
                    for (int n = 0; n < 2; ++n) acc[m][n] = (f32x4)(0.f);
            }
        }
    }
    __syncthreads();

    // ========== P-D: FFN2 K=512, rounds 16..23 + LN2 -> out ==========
    {
        f32x4 acc[2][2];
        #pragma unroll
        for (int m = 0; m < 2; ++m)
            #pragma unroll
            for (int n = 0; n < 2; ++n) acc[m][n] = (f32x4)(0.f);

        #pragma unroll
        for (int i = 16; i < 24; ++i) {
            NSTAGE(i + 2);
            const int k = i - 16;
            char* Bs = stbuf(i);
            #pragma unroll
            for (int ks = 0; ks < 2; ++ks) {
                bf16x8 af[2], bfr[2];
                #pragma unroll
                for (int m = 0; m < 2; ++m) {
                    const int r = m * 16 + (lane & 15);
                    const int ch = k * 8 + ks * 4 + (lane >> 4);
                    af[m] = *(const bf16x8*)(smH + r * 1024 + ((ch ^ (r & 7)) << 4));
                }
                #pragma unroll
                for (int n = 0; n < 2; ++n) {
                    const int rB = wid * 32 + n * 16 + (lane & 15);
                    bfr[n] = *(const bf16x8*)(Bs + rB * 128
                             + (((ks * 4 + (lane >> 4)) ^ (rB & 7)) << 4));
                }
                #pragma unroll
                for (int m = 0; m < 2; ++m)
                    #pragma unroll
                    for (int n = 0; n < 2; ++n)
                        acc[m][n] = __builtin_amdgcn_mfma_f32_16x16x32_bf16(
                            af[m], bfr[n], acc[m][n], 0, 0, 0);
            }
            if (i + 2 < 24) bar_vm4(); else bar_vm0();
        }

        // LN2 epilogue -> out
        float v[2][2][4], s[2][4], sq[2][4];
        #pragma unroll
        for (int m = 0; m < 2; ++m)
            #pragma unroll
            for (int j = 0; j < 4; ++j) { s[m][j] = 0.f; sq[m][j] = 0.f; }
        #pragma unroll
        for (int n = 0; n < 2; ++n) {
            const int c = wid * 32 + n * 16 + (lane & 15);
            const float bv = b2[c];
            #pragma unroll
            for (int m = 0; m < 2; ++m) {
                #pragma unroll
                for (int j = 0; j < 4; ++j) {
                    float x = acc[m][n][j] + bv + xres[m][n][j];
                    v[m][n][j] = x; s[m][j] += x; sq[m][j] += x * x;
                }
            }
        }
        #pragma unroll
        for (int m = 0; m < 2; ++m)
            #pragma unroll
            for (int j = 0; j < 4; ++j) {
                #pragma unroll
                for (int msk = 1; msk <= 8; msk <<= 1) {
                    s[m][j]  += __shfl_xor(s[m][j], msk);
                    sq[m][j] += __shfl_xor(sq[m][j], msk);
                }
                if ((lane & 15) == 0) {
                    const int r = m * 16 + ((lane >> 4) << 2) + j;
                    part[(wid * 32 + r) * 2 + 0] = s[m][j];
                    part[(wid * 32 + r) * 2 + 1] = sq[m][j];
                }
            }
        __syncthreads();
        #pragma unroll
        for (int m = 0; m < 2; ++m) {
            const int rb = m * 16 + ((lane >> 4) << 2);
            #pragma unroll
            for (int j = 0; j < 4; ++j) {
                const int r = rb + j;
                float S = 0.f, SQ = 0.f;
                #pragma unroll
                for (int w = 0; w < 8; ++w) {
                    S += part[(w * 32 + r) * 2 + 0]; SQ += part[(w * 32 + r) * 2 + 1];
                }
                const float mean = S * (1.f / 256.f);
                const float var  = SQ * (1.f / 256.f) - mean * mean;
                const float rstd = rsqrtf(var + LN_EPS);
                #pragma unroll
                for (int n = 0; n < 2; ++n) {
                    const int c = wid * 32 + n * 16 + (lane & 15);
                    out[(size_t)(m0 + r) * 256 + c] =
                        (v[m][n][j] - mean) * rstd * g2[c] + be2[c];
                }
            }
        }
    }
}

// ---------------------------------------------------------------------------
extern "C" void kernel_launch(void* const* d_in, const int* in_sizes, int n_in,
                              void* d_out, int out_size, void* d_ws, size_t ws_size,
                              hipStream_t stream) {
    const float* features = (const float*)d_in[0];
    const float* w_qkv    = (const float*)d_in[1];
    const float* b_qkv    = (const float*)d_in[2];
    const float* w_out    = (const float*)d_in[3];
    const float* b_out    = (const float*)d_in[4];
    const float* w1       = (const float*)d_in[5];
    const float* b1       = (const float*)d_in[6];
    const float* w2       = (const float*)d_in[7];
    const float* b2       = (const float*)d_in[8];
    const float* g1       = (const float*)d_in[9];
    const float* be1      = (const float*)d_in[10];
    const float* g2       = (const float*)d_in[11];
    const float* be2      = (const float*)d_in[12];
    // d_in[13] (mask) structurally determined by WIN=9 -> not read.

    unsigned short* wsu = (unsigned short*)d_ws;
    unsigned short* wconv = wsu;                // wq|wo|w1|w2 bf16: 393,216 els
    unsigned short* kvbf  = wsu + 393216;       // [8192][512]

    // 1) K,V projection (fp32-direct) + weight conversion (incl. Wq)
    kv_gemm_f32<<<dim3(64, 4), 512, 0, stream>>>(
        features, w_qkv, b_qkv, w_out, w1, w2, kvbf, wconv);
    // 2) fused tail: Q GEMM -> attention -> out-proj+LN1 -> FFN1 -> FFN2+LN2
    tail_fused_pipe2<<<M_ROWS / 32, 512, 0, stream>>>(
        kvbf, wconv, features, b_qkv, b_out, g1, be1, b1, b2, g2, be2,
        (float*)d_out);
}